// Round 3
// baseline (1135.068 us; speedup 1.0000x reference)
//
#include <hip/hip_runtime.h>

typedef __bf16 bf16x8 __attribute__((ext_vector_type(8)));
typedef __bf16 bf16x4 __attribute__((ext_vector_type(4)));
typedef float  f32x4  __attribute__((ext_vector_type(4)));

#define D_MODEL 1024
#define SEQ     2048
#define BATCH   2
#define NH      16
#define DH      64
#define HID     4096
#define ROWS    (BATCH*SEQ)

// ------------------------------------------- LayerNorm: fp32 in, bf16 out
__global__ __launch_bounds__(256) void ln_kernel(
    const float* __restrict__ x, const float* __restrict__ g,
    const float* __restrict__ b, __bf16* __restrict__ out)
{
  int row = blockIdx.x;
  const float* xr = x + (size_t)row * D_MODEL;
  int i0 = threadIdx.x * 4;
  f32x4 xv = *(const f32x4*)(xr + i0);
  float s  = xv[0] + xv[1] + xv[2] + xv[3];
  float ss = xv[0]*xv[0] + xv[1]*xv[1] + xv[2]*xv[2] + xv[3]*xv[3];
#pragma unroll
  for (int off = 1; off < 64; off <<= 1) {
    s  += __shfl_xor(s,  off, 64);
    ss += __shfl_xor(ss, off, 64);
  }
  __shared__ float red[8];
  int wave = threadIdx.x >> 6;
  if ((threadIdx.x & 63) == 0) { red[wave] = s; red[4 + wave] = ss; }
  __syncthreads();
  s  = red[0] + red[1] + red[2] + red[3];
  ss = red[4] + red[5] + red[6] + red[7];
  float mu  = s * (1.0f / D_MODEL);
  float var = ss * (1.0f / D_MODEL) - mu * mu;
  float inv = rsqrtf(var + 1e-5f);
  f32x4 gv = *(const f32x4*)(g + i0);
  f32x4 bv = *(const f32x4*)(b + i0);
  bf16x4 ov;
#pragma unroll
  for (int j = 0; j < 4; ++j)
    ov[j] = (__bf16)((xv[j] - mu) * inv * gv[j] + bv[j]);
  *(bf16x4*)(out + (size_t)row * D_MODEL + i0) = ov;
}

// ------------------------------------------------------- Generic MFMA GEMM
// C[M,N] = act(A[M,K] @ B[K,N] + bias) (+ resid). A bf16, B/bias/resid fp32,
// C bf16 or fp32 (c_fp32). 64x64 tile, BK=32, 4 waves = 32x32 quadrants.
__global__ __launch_bounds__(256) void gemm_kernel(
    const __bf16* __restrict__ A, const float* __restrict__ Bm,
    const float* __restrict__ bias, const float* __restrict__ resid,
    void* __restrict__ Cv, int M, int N, int K, int act, int c_fp32)
{
  __shared__ __bf16 As[64 * 40];  // [m][k], stride 40 (2-way alias: free)
  __shared__ __bf16 Bs[64 * 40];  // [n][k] (transposed at staging)
  int tid  = threadIdx.x, lane = tid & 63, wave = tid >> 6;
  int wr   = wave >> 1,  wc   = wave & 1;
  int quad = lane >> 4,  l16  = lane & 15;
  int row0 = blockIdx.x * 64, col0 = blockIdx.y * 64;
  int ra = tid >> 2, ka = (tid & 3) << 3;   // A stage: row 0..63, 8 cols
  int kb = tid >> 3, nb = (tid & 7) << 3;   // B stage: k 0..31, 8 cols
  f32x4 acc[2][2] = {};

  for (int k0 = 0; k0 < K; k0 += 32) {
    bf16x8 av = *(const bf16x8*)(A + (size_t)(row0 + ra) * K + k0 + ka);
    const float* bp = Bm + (size_t)(k0 + kb) * N + col0 + nb;
    f32x4 b0 = *(const f32x4*)(bp);
    f32x4 b1 = *(const f32x4*)(bp + 4);
    *(bf16x8*)(As + ra * 40 + ka) = av;
#pragma unroll
    for (int i = 0; i < 4; ++i) {
      Bs[(nb + i) * 40 + kb]     = (__bf16)b0[i];
      Bs[(nb + 4 + i) * 40 + kb] = (__bf16)b1[i];
    }
    __syncthreads();
    bf16x8 af0 = *(const bf16x8*)(As + (wr * 32 +      l16) * 40 + quad * 8);
    bf16x8 af1 = *(const bf16x8*)(As + (wr * 32 + 16 + l16) * 40 + quad * 8);
    bf16x8 bf0 = *(const bf16x8*)(Bs + (wc * 32 +      l16) * 40 + quad * 8);
    bf16x8 bf1 = *(const bf16x8*)(Bs + (wc * 32 + 16 + l16) * 40 + quad * 8);
    acc[0][0] = __builtin_amdgcn_mfma_f32_16x16x32_bf16(af0, bf0, acc[0][0], 0, 0, 0);
    acc[0][1] = __builtin_amdgcn_mfma_f32_16x16x32_bf16(af0, bf1, acc[0][1], 0, 0, 0);
    acc[1][0] = __builtin_amdgcn_mfma_f32_16x16x32_bf16(af1, bf0, acc[1][0], 0, 0, 0);
    acc[1][1] = __builtin_amdgcn_mfma_f32_16x16x32_bf16(af1, bf1, acc[1][1], 0, 0, 0);
    __syncthreads();
  }
#pragma unroll
  for (int i = 0; i < 2; ++i) {
#pragma unroll
    for (int j = 0; j < 2; ++j) {
      int gcol = col0 + wc * 32 + j * 16 + l16;
      float bsv = bias[gcol];
#pragma unroll
      for (int r = 0; r < 4; ++r) {
        int grow = row0 + wr * 32 + i * 16 + quad * 4 + r;
        float v = acc[i][j][r] + bsv;
        if (act) v = 0.5f * v * (1.0f + erff(v * 0.70710678118654752f));
        if (resid) v += resid[(size_t)grow * N + gcol];
        if (c_fp32) ((float*)Cv)[(size_t)grow * N + gcol] = v;
        else        ((__bf16*)Cv)[(size_t)grow * N + gcol] = (__bf16)v;
      }
    }
  }
}

// ---------------------------------------------- RoPE (full-D pairs), in place
// Reference ropes the FULL 1024-dim vector: pair (i, i+512) (crosses heads).
// Each thread owns a full (i, i+512) pair for q and k -> race-free in place.
__global__ __launch_bounds__(256) void rope_inplace(
    __bf16* __restrict__ ql, __bf16* __restrict__ kl,
    const int* __restrict__ pos)
{
  int row = blockIdx.x;                 // b*SEQ + n
  int n = row & (SEQ - 1);
  float p = (float)pos[n];
  const size_t rbase = (size_t)row * D_MODEL;
#pragma unroll
  for (int t = 0; t < 2; ++t) {
    int i = threadIdx.x + t * 256;      // 0..511
    float fr  = expf(-9.210340371976184f * ((float)i * (1.0f / 512.0f))); // ln(1e4)
    float ang = p * fr;
    float sn, c;
    sincosf(ang, &sn, &c);
    float q1 = (float)ql[rbase + i], q2 = (float)ql[rbase + 512 + i];
    float k1 = (float)kl[rbase + i], k2 = (float)kl[rbase + 512 + i];
    ql[rbase + i]       = (__bf16)(q1 * c - q2 * sn);
    ql[rbase + 512 + i] = (__bf16)(q1 * sn + q2 * c);
    kl[rbase + i]       = (__bf16)(k1 * c - k2 * sn);
    kl[rbase + 512 + i] = (__bf16)(k1 * sn + k2 * c);
  }
}

// --------------------------------------------------- Flash attention (fwd)
// One wave = 16 queries, online softmax over key-tiles of 32.
// Q,K,V in [B, SEQ, NH*DH] layout (row stride D_MODEL), head offset h*DH.
__global__ __launch_bounds__(256) void attn_kernel(
    const __bf16* __restrict__ Q, const __bf16* __restrict__ K,
    const __bf16* __restrict__ V, __bf16* __restrict__ ctx)
{
  __shared__ __bf16 Pl[4][16 * 40];     // per-wave P tile, stride 40
  int tid = threadIdx.x, lane = tid & 63, wave = tid >> 6;
  int quad = lane >> 4, l16 = lane & 15;
  int blk = blockIdx.x;
  int q64 = blk & 31;                   // SEQ/64 = 32
  int bh  = blk >> 5;                   // 0..31 (= b*NH + h)
  int b = bh >> 4, h = bh & 15;
  int q0  = q64 * 64 + wave * 16;
  const size_t rowbase = (size_t)b * SEQ * D_MODEL + h * DH;
  const __bf16* qp = Q + rowbase + (size_t)(q0 + l16) * D_MODEL + quad * 8;
  bf16x8 qf0 = *(const bf16x8*)(qp);
  bf16x8 qf1 = *(const bf16x8*)(qp + 32);
  float mrow[4] = {-1e30f, -1e30f, -1e30f, -1e30f};
  float lrow[4] = {0.f, 0.f, 0.f, 0.f};
  f32x4 acc[4] = {};
  __bf16* pw = &Pl[wave][0];

  for (int kb = 0; kb < SEQ; kb += 32) {
    f32x4 s[2];
#pragma unroll
    for (int t = 0; t < 2; ++t) {
      const __bf16* kp = K + rowbase + (size_t)(kb + t * 16 + l16) * D_MODEL;
      bf16x8 kf0 = *(const bf16x8*)(kp + quad * 8);
      bf16x8 kf1 = *(const bf16x8*)(kp + 32 + quad * 8);
      f32x4 z = {};
      z = __builtin_amdgcn_mfma_f32_16x16x32_bf16(qf0, kf0, z, 0, 0, 0);
      z = __builtin_amdgcn_mfma_f32_16x16x32_bf16(qf1, kf1, z, 0, 0, 0);
#pragma unroll
      for (int r = 0; r < 4; ++r) s[t][r] = z[r] * 0.125f;  // 1/sqrt(64)
    }
#pragma unroll
    for (int r = 0; r < 4; ++r) {
      float mx = fmaxf(s[0][r], s[1][r]);
#pragma unroll
      for (int off = 1; off < 16; off <<= 1) mx = fmaxf(mx, __shfl_xor(mx, off, 64));
      float mn = fmaxf(mrow[r], mx);
      float al = __expf(mrow[r] - mn);
      float p0 = __expf(s[0][r] - mn);
      float p1 = __expf(s[1][r] - mn);
      float rs = p0 + p1;
#pragma unroll
      for (int off = 1; off < 16; off <<= 1) rs += __shfl_xor(rs, off, 64);
      lrow[r] = lrow[r] * al + rs;
      mrow[r] = mn;
#pragma unroll
      for (int j = 0; j < 4; ++j) acc[j][r] *= al;
      pw[(quad * 4 + r) * 40 + l16]      = (__bf16)p0;  // C-layout -> LDS
      pw[(quad * 4 + r) * 40 + 16 + l16] = (__bf16)p1;
    }
    __syncthreads();   // orders P writes before cross-lane reads
    bf16x8 pf = *(const bf16x8*)(pw + l16 * 40 + quad * 8);  // A-layout read
    const __bf16* vp = V + rowbase + (size_t)(kb + quad * 8) * D_MODEL + l16;
#pragma unroll
    for (int j = 0; j < 4; ++j) {
      bf16x8 vf;
#pragma unroll
      for (int jj = 0; jj < 8; ++jj) vf[jj] = vp[(size_t)jj * D_MODEL + j * 16];
      acc[j] = __builtin_amdgcn_mfma_f32_16x16x32_bf16(pf, vf, acc[j], 0, 0, 0);
    }
    __syncthreads();   // protect P tile before next iteration's writes
  }
#pragma unroll
  for (int r = 0; r < 4; ++r) {
    int row = q0 + quad * 4 + r;
    float inv = 1.0f / lrow[r];
    size_t obase = ((size_t)(b * SEQ) + row) * D_MODEL + h * DH;
#pragma unroll
    for (int j = 0; j < 4; ++j)
      ctx[obase + j * 16 + l16] = (__bf16)(acc[j][r] * inv);
  }
}

// ------------------------------------------------------------------ launcher
extern "C" void kernel_launch(void* const* d_in, const int* in_sizes, int n_in,
                              void* d_out, int out_size, void* d_ws, size_t ws_size,
                              hipStream_t stream)
{
  const float* x   = (const float*)d_in[0];
  const int*   pos = (const int*)  d_in[1];
  const float* Wq  = (const float*)d_in[2];
  const float* bq  = (const float*)d_in[3];
  const float* Wk  = (const float*)d_in[4];
  const float* bk  = (const float*)d_in[5];
  const float* Wv  = (const float*)d_in[6];
  const float* bv  = (const float*)d_in[7];
  const float* Wo  = (const float*)d_in[8];
  const float* bo  = (const float*)d_in[9];
  const float* g1  = (const float*)d_in[10];
  const float* b1  = (const float*)d_in[11];
  const float* g2  = (const float*)d_in[12];
  const float* b2  = (const float*)d_in[13];
  const float* W1  = (const float*)d_in[14];
  const float* bm1 = (const float*)d_in[15];
  const float* W2  = (const float*)d_in[16];
  const float* bm2 = (const float*)d_in[17];
  float* out = (float*)d_out;

  // Workspace: 32 MB total.
  //   [ 0, 8)  hln (bf16) -> ctx (bf16) -> hmlp chunk (bf16)
  //   [ 8,24)  qlin[8,16) + klin[16,24) (bf16) -> x1 (fp32, 16 MB)
  //   [24,32)  vlin (bf16) -> hln2 (bf16)
  const size_t MB = 1024 * 1024;
  char* w = (char*)d_ws;
  __bf16* hln  = (__bf16*)(w + 0 * MB);
  __bf16* qlin = (__bf16*)(w + 8 * MB);
  __bf16* klin = (__bf16*)(w + 16 * MB);
  __bf16* vlin = (__bf16*)(w + 24 * MB);
  __bf16* ctx  = hln;
  float*  x1   = (float*)(w + 8 * MB);
  __bf16* hln2 = vlin;
  __bf16* hmlp = hln;    // 8 MB: one 1024-row chunk of [ROWS, HID] bf16

  dim3 blk(256);
  dim3 gD(ROWS / 64, D_MODEL / 64);       // 64 x 16

  ln_kernel<<<ROWS, blk, 0, stream>>>(x, g1, b1, hln);
  gemm_kernel<<<gD, blk, 0, stream>>>(hln, Wq, bq, nullptr, qlin, ROWS, D_MODEL, D_MODEL, 0, 0);
  gemm_kernel<<<gD, blk, 0, stream>>>(hln, Wk, bk, nullptr, klin, ROWS, D_MODEL, D_MODEL, 0, 0);
  gemm_kernel<<<gD, blk, 0, stream>>>(hln, Wv, bv, nullptr, vlin, ROWS, D_MODEL, D_MODEL, 0, 0);
  rope_inplace<<<ROWS, blk, 0, stream>>>(qlin, klin, pos);
  attn_kernel<<<BATCH * NH * (SEQ / 64), blk, 0, stream>>>(qlin, klin, vlin, ctx);
  gemm_kernel<<<gD, blk, 0, stream>>>(ctx, Wo, bo, x, x1, ROWS, D_MODEL, D_MODEL, 0, 1);
  ln_kernel<<<ROWS, blk, 0, stream>>>(x1, g2, b2, hln2);

  // MLP in 4 row-chunks of 1024 so the GELU intermediate fits in 8 MB.
  const int CH = 1024;
  dim3 gW1(CH / 64, HID / 64);            // 16 x 64
  dim3 gW2(CH / 64, D_MODEL / 64);        // 16 x 16
  for (int c = 0; c < ROWS / CH; ++c) {
    const __bf16* a1 = hln2 + (size_t)c * CH * D_MODEL;
    gemm_kernel<<<gW1, blk, 0, stream>>>(a1, W1, bm1, nullptr, hmlp, CH, HID, D_MODEL, 1, 0);
    gemm_kernel<<<gW2, blk, 0, stream>>>(hmlp, W2, bm2, x1 + (size_t)c * CH * D_MODEL,
                                         out + (size_t)c * CH * D_MODEL, CH, D_MODEL, HID, 0, 1);
  }
}

// Round 4
// 802.953 us; speedup vs baseline: 1.4136x; 1.4136x over previous
//
#include <hip/hip_runtime.h>

typedef __bf16 bf16x8 __attribute__((ext_vector_type(8)));
typedef __bf16 bf16x4 __attribute__((ext_vector_type(4)));
typedef float  f32x4  __attribute__((ext_vector_type(4)));

#define D_MODEL 1024
#define SEQ     2048
#define BATCH   2
#define NH      16
#define DH      64
#define HID     4096
#define ROWS    (BATCH*SEQ)

static __device__ __forceinline__ void gl_lds16(const __bf16* g, __bf16* l) {
  __builtin_amdgcn_global_load_lds(
      (const __attribute__((address_space(1))) unsigned int*)g,
      (__attribute__((address_space(3))) unsigned int*)l, 16, 0, 0);
}

// ------------------------------------------- LayerNorm: fp32 in, bf16 out
__global__ __launch_bounds__(256) void ln_kernel(
    const float* __restrict__ x, const float* __restrict__ g,
    const float* __restrict__ b, __bf16* __restrict__ out)
{
  int row = blockIdx.x;
  const float* xr = x + (size_t)row * D_MODEL;
  int i0 = threadIdx.x * 4;
  f32x4 xv = *(const f32x4*)(xr + i0);
  float s  = xv[0] + xv[1] + xv[2] + xv[3];
  float ss = xv[0]*xv[0] + xv[1]*xv[1] + xv[2]*xv[2] + xv[3]*xv[3];
#pragma unroll
  for (int off = 1; off < 64; off <<= 1) {
    s  += __shfl_xor(s,  off, 64);
    ss += __shfl_xor(ss, off, 64);
  }
  __shared__ float red[8];
  int wave = threadIdx.x >> 6;
  if ((threadIdx.x & 63) == 0) { red[wave] = s; red[4 + wave] = ss; }
  __syncthreads();
  s  = red[0] + red[1] + red[2] + red[3];
  ss = red[4] + red[5] + red[6] + red[7];
  float mu  = s * (1.0f / D_MODEL);
  float var = ss * (1.0f / D_MODEL) - mu * mu;
  float inv = rsqrtf(var + 1e-5f);
  f32x4 gv = *(const f32x4*)(g + i0);
  f32x4 bv = *(const f32x4*)(b + i0);
  bf16x4 ov;
#pragma unroll
  for (int j = 0; j < 4; ++j)
    ov[j] = (__bf16)((xv[j] - mu) * inv * gv[j] + bv[j]);
  *(bf16x4*)(out + (size_t)row * D_MODEL + i0) = ov;
}

// ---------------------- Weight convert+transpose: fp32 [K][N] -> bf16 [N][K]
__global__ __launch_bounds__(256) void convT_kernel(
    const float* __restrict__ W, __bf16* __restrict__ Wt, int K, int N)
{
  __shared__ float T[32][33];
  int n0 = blockIdx.x * 32, k0 = blockIdx.y * 32;
  int r  = threadIdx.x >> 3;         // 0..31
  int c4 = (threadIdx.x & 7) * 4;    // 0..28
  f32x4 v = *(const f32x4*)(W + (size_t)(k0 + r) * N + n0 + c4);
#pragma unroll
  for (int i = 0; i < 4; ++i) T[r][c4 + i] = v[i];
  __syncthreads();
  bf16x4 o;
#pragma unroll
  for (int i = 0; i < 4; ++i) o[i] = (__bf16)T[c4 + i][r];
  *(bf16x4*)(Wt + (size_t)(n0 + r) * K + k0 + c4) = o;
}

// ------------------------------------------------- m97-style 128x128 GEMM
// C[M,N] = act(A[M,K] @ Bt[N,K]^T + bias) (+resid). A,Bt bf16; bias/resid fp32.
// BK=32, 4 waves each 64x64, global_load_lds staging, 16 MFMA/wave/K-step.
__global__ __launch_bounds__(256) void gemm128(
    const __bf16* __restrict__ A, const __bf16* __restrict__ Bt,
    const float* __restrict__ bias, const float* __restrict__ resid,
    void* __restrict__ Cv, int M, int N, int K, int act, int c_fp32)
{
  __shared__ __bf16 As[128 * 32];   // [m][k], no pad (global_load_lds)
  __shared__ __bf16 Bs[128 * 32];   // [n][k]
  int tid = threadIdx.x, lane = tid & 63, wv = tid >> 6;
  int quad = lane >> 4, l16 = lane & 15;
  int wr = wv >> 1, wc = wv & 1;
  int row0 = blockIdx.x * 128, col0 = blockIdx.y * 128;
  int srow = lane >> 2, skseg = (lane & 3) * 8;
  f32x4 acc[4][4] = {};

  for (int k0 = 0; k0 < K; k0 += 32) {
#pragma unroll
    for (int q = 0; q < 2; ++q) {
      int c = q * 4 + wv;
      int r = c * 16 + srow;
      gl_lds16(A  + (size_t)(row0 + r) * K + k0 + skseg, As + c * 512);
      gl_lds16(Bt + (size_t)(col0 + r) * K + k0 + skseg, Bs + c * 512);
    }
    __syncthreads();
    bf16x8 af[4], bf[4];
#pragma unroll
    for (int i = 0; i < 4; ++i) {
      af[i] = *(const bf16x8*)(As + (wr * 64 + i * 16 + l16) * 32 + quad * 8);
      bf[i] = *(const bf16x8*)(Bs + (wc * 64 + i * 16 + l16) * 32 + quad * 8);
    }
#pragma unroll
    for (int i = 0; i < 4; ++i)
#pragma unroll
      for (int j = 0; j < 4; ++j)
        acc[i][j] = __builtin_amdgcn_mfma_f32_16x16x32_bf16(af[i], bf[j], acc[i][j], 0, 0, 0);
    __syncthreads();
  }
#pragma unroll
  for (int i = 0; i < 4; ++i) {
    int grow = row0 + wr * 64 + i * 16 + quad * 4;
#pragma unroll
    for (int j = 0; j < 4; ++j) {
      int gcol = col0 + wc * 64 + j * 16 + l16;
      float bsv = bias[gcol];
#pragma unroll
      for (int r = 0; r < 4; ++r) {
        size_t off = (size_t)(grow + r) * N + gcol;
        float v = acc[i][j][r] + bsv;
        if (act) v = 0.5f * v * (1.0f + erff(v * 0.70710678118654752f));
        if (resid) v += resid[off];
        if (c_fp32) ((float*)Cv)[off] = v;
        else        ((__bf16*)Cv)[off] = (__bf16)v;
      }
    }
  }
}

// ---------------------------------------------- RoPE (full-D pairs), in place
__global__ __launch_bounds__(256) void rope_inplace(
    __bf16* __restrict__ ql, __bf16* __restrict__ kl,
    const int* __restrict__ pos)
{
  int row = blockIdx.x;
  int n = row & (SEQ - 1);
  float p = (float)pos[n];
  const size_t rbase = (size_t)row * D_MODEL;
#pragma unroll
  for (int t = 0; t < 2; ++t) {
    int i = threadIdx.x + t * 256;
    float fr  = expf(-9.210340371976184f * ((float)i * (1.0f / 512.0f)));
    float ang = p * fr;
    float sn, c;
    sincosf(ang, &sn, &c);
    float q1 = (float)ql[rbase + i], q2 = (float)ql[rbase + 512 + i];
    float k1 = (float)kl[rbase + i], k2 = (float)kl[rbase + 512 + i];
    ql[rbase + i]       = (__bf16)(q1 * c - q2 * sn);
    ql[rbase + 512 + i] = (__bf16)(q1 * sn + q2 * c);
    kl[rbase + i]       = (__bf16)(k1 * c - k2 * sn);
    kl[rbase + 512 + i] = (__bf16)(k1 * sn + k2 * c);
  }
}

// --------------------------------------------------- Flash attention (fwd)
// Block = 64 queries (4 waves x 16), key tiles of 64 staged in LDS.
// Q,K,V in [B,SEQ,NH*DH] (row stride D_MODEL), head offset h*DH.
#define KSTR 76
__global__ __launch_bounds__(256) void attn_kernel(
    const __bf16* __restrict__ Q, const __bf16* __restrict__ K,
    const __bf16* __restrict__ V, __bf16* __restrict__ ctx)
{
  __shared__ __bf16 Ks[64 * KSTR];     // [key][d]
  __shared__ __bf16 Vt[64 * KSTR];     // [d][key]
  __shared__ __bf16 Pl[4][16 * KSTR];  // per-wave P [qrow][key]
  int tid = threadIdx.x, lane = tid & 63, wave = tid >> 6;
  int quad = lane >> 4, l16 = lane & 15;
  int blk = blockIdx.x;
  int q64 = blk & 31;
  int bh  = blk >> 5;
  int b = bh >> 4, h = bh & 15;
  int q0 = q64 * 64 + wave * 16;
  const size_t rowbase = (size_t)b * SEQ * D_MODEL + h * DH;
  const __bf16* qp = Q + rowbase + (size_t)(q0 + l16) * D_MODEL + quad * 8;
  bf16x8 qf0 = *(const bf16x8*)(qp);
  bf16x8 qf1 = *(const bf16x8*)(qp + 32);
  float mrow[4] = {-1e30f, -1e30f, -1e30f, -1e30f};
  float lrow[4] = {0.f, 0.f, 0.f, 0.f};
  f32x4 acc[4] = {};
  __bf16* pw = &Pl[wave][0];
  int sn   = tid >> 3;             // 0..31
  int sseg = (tid & 7) * 8;        // d offset

  for (int kb = 0; kb < SEQ; kb += 64) {
    __syncthreads();  // previous tile fully consumed before restaging
#pragma unroll
    for (int t = 0; t < 2; ++t) {
      int n = sn + t * 32;
      const __bf16* src = K + rowbase + (size_t)(kb + n) * D_MODEL + sseg;
      *(bf16x8*)(Ks + n * KSTR + sseg) = *(const bf16x8*)src;
      bf16x8 vv = *(const bf16x8*)(V + rowbase + (size_t)(kb + n) * D_MODEL + sseg);
#pragma unroll
      for (int i = 0; i < 8; ++i) Vt[(sseg + i) * KSTR + n] = vv[i];
    }
    __syncthreads();
    // scores for 4 key-tiles of 16
    f32x4 s[4];
#pragma unroll
    for (int j = 0; j < 4; ++j) {
      const __bf16* kr = Ks + (j * 16 + l16) * KSTR;
      bf16x8 kf0 = *(const bf16x8*)(kr + quad * 8);
      bf16x8 kf1 = *(const bf16x8*)(kr + 32 + quad * 8);
      f32x4 z = {};
      z = __builtin_amdgcn_mfma_f32_16x16x32_bf16(qf0, kf0, z, 0, 0, 0);
      z = __builtin_amdgcn_mfma_f32_16x16x32_bf16(qf1, kf1, z, 0, 0, 0);
#pragma unroll
      for (int r = 0; r < 4; ++r) s[j][r] = z[r] * 0.125f;
    }
    // online softmax per accumulator row
#pragma unroll
    for (int r = 0; r < 4; ++r) {
      float mx = fmaxf(fmaxf(s[0][r], s[1][r]), fmaxf(s[2][r], s[3][r]));
#pragma unroll
      for (int off = 1; off < 16; off <<= 1) mx = fmaxf(mx, __shfl_xor(mx, off, 64));
      float mn = fmaxf(mrow[r], mx);
      float al = __expf(mrow[r] - mn);
      float p0 = __expf(s[0][r] - mn);
      float p1 = __expf(s[1][r] - mn);
      float p2 = __expf(s[2][r] - mn);
      float p3 = __expf(s[3][r] - mn);
      float rs = (p0 + p1) + (p2 + p3);
#pragma unroll
      for (int off = 1; off < 16; off <<= 1) rs += __shfl_xor(rs, off, 64);
      lrow[r] = lrow[r] * al + rs;
      mrow[r] = mn;
#pragma unroll
      for (int j = 0; j < 4; ++j) acc[j][r] *= al;
      int prow = (quad * 4 + r) * KSTR;
      pw[prow + l16]      = (__bf16)p0;
      pw[prow + 16 + l16] = (__bf16)p1;
      pw[prow + 32 + l16] = (__bf16)p2;
      pw[prow + 48 + l16] = (__bf16)p3;
    }
    // PV: P per-wave (no barrier needed), fragments all vector LDS reads
    bf16x8 pf0 = *(const bf16x8*)(pw + l16 * KSTR + quad * 8);
    bf16x8 pf1 = *(const bf16x8*)(pw + l16 * KSTR + 32 + quad * 8);
#pragma unroll
    for (int j = 0; j < 4; ++j) {
      const __bf16* vr = Vt + (j * 16 + l16) * KSTR;
      bf16x8 vf0 = *(const bf16x8*)(vr + quad * 8);
      bf16x8 vf1 = *(const bf16x8*)(vr + 32 + quad * 8);
      acc[j] = __builtin_amdgcn_mfma_f32_16x16x32_bf16(pf0, vf0, acc[j], 0, 0, 0);
      acc[j] = __builtin_amdgcn_mfma_f32_16x16x32_bf16(pf1, vf1, acc[j], 0, 0, 0);
    }
  }
#pragma unroll
  for (int r = 0; r < 4; ++r) {
    int row = q0 + quad * 4 + r;
    float inv = 1.0f / lrow[r];
    size_t obase = ((size_t)(b * SEQ) + row) * D_MODEL + h * DH;
#pragma unroll
    for (int j = 0; j < 4; ++j)
      ctx[obase + j * 16 + l16] = (__bf16)(acc[j][r] * inv);
  }
}

// ------------------------------------------------------------------ launcher
extern "C" void kernel_launch(void* const* d_in, const int* in_sizes, int n_in,
                              void* d_out, int out_size, void* d_ws, size_t ws_size,
                              hipStream_t stream)
{
  const float* x   = (const float*)d_in[0];
  const int*   pos = (const int*)  d_in[1];
  const float* Wq  = (const float*)d_in[2];
  const float* bq  = (const float*)d_in[3];
  const float* Wk  = (const float*)d_in[4];
  const float* bk  = (const float*)d_in[5];
  const float* Wv  = (const float*)d_in[6];
  const float* bv  = (const float*)d_in[7];
  const float* Wo  = (const float*)d_in[8];
  const float* bo  = (const float*)d_in[9];
  const float* g1  = (const float*)d_in[10];
  const float* b1  = (const float*)d_in[11];
  const float* g2  = (const float*)d_in[12];
  const float* b2  = (const float*)d_in[13];
  const float* W1  = (const float*)d_in[14];
  const float* bm1 = (const float*)d_in[15];
  const float* W2  = (const float*)d_in[16];
  const float* bm2 = (const float*)d_in[17];
  float* out = (float*)d_out;

  const size_t MB = 1024 * 1024;
  char* w = (char*)d_ws;
  dim3 blk(256);
  dim3 gConvD(D_MODEL / 32, D_MODEL / 32);   // 32x32
  dim3 gConv1(HID / 32, D_MODEL / 32);       // W1: K=1024,N=4096 -> (128,32)
  dim3 gConv2(D_MODEL / 32, HID / 32);       // W2: K=4096,N=1024 -> (32,128)
  dim3 gQKV(ROWS / 128, D_MODEL / 128);      // 32x8

  if (ws_size >= (size_t)96 * MB) {
    // ---------- large-workspace path: full-size MLP, big grids ----------
    __bf16* hln  = (__bf16*)(w + 0 * MB);    // later hln2
    __bf16* qlin = (__bf16*)(w + 8 * MB);    // later W1T
    __bf16* klin = (__bf16*)(w + 16 * MB);   // later W2T
    __bf16* vlin = (__bf16*)(w + 24 * MB);
    __bf16* ctx  = (__bf16*)(w + 32 * MB);
    float*  x1   = (float*) (w + 40 * MB);   // 16 MB fp32
    __bf16* hmlp = (__bf16*)(w + 56 * MB);   // 32 MB
    __bf16* WqT  = (__bf16*)(w + 88 * MB);
    __bf16* WkT  = (__bf16*)(w + 90 * MB);
    __bf16* WvT  = (__bf16*)(w + 92 * MB);
    __bf16* WoT  = (__bf16*)(w + 94 * MB);
    __bf16* W1T  = (__bf16*)(w + 8 * MB);
    __bf16* W2T  = (__bf16*)(w + 16 * MB);

    convT_kernel<<<gConvD, blk, 0, stream>>>(Wq, WqT, D_MODEL, D_MODEL);
    convT_kernel<<<gConvD, blk, 0, stream>>>(Wk, WkT, D_MODEL, D_MODEL);
    convT_kernel<<<gConvD, blk, 0, stream>>>(Wv, WvT, D_MODEL, D_MODEL);
    convT_kernel<<<gConvD, blk, 0, stream>>>(Wo, WoT, D_MODEL, D_MODEL);
    ln_kernel<<<ROWS, blk, 0, stream>>>(x, g1, b1, hln);
    gemm128<<<gQKV, blk, 0, stream>>>(hln, WqT, bq, nullptr, qlin, ROWS, D_MODEL, D_MODEL, 0, 0);
    gemm128<<<gQKV, blk, 0, stream>>>(hln, WkT, bk, nullptr, klin, ROWS, D_MODEL, D_MODEL, 0, 0);
    gemm128<<<gQKV, blk, 0, stream>>>(hln, WvT, bv, nullptr, vlin, ROWS, D_MODEL, D_MODEL, 0, 0);
    rope_inplace<<<ROWS, blk, 0, stream>>>(qlin, klin, pos);
    attn_kernel<<<BATCH * NH * (SEQ / 64), blk, 0, stream>>>(qlin, klin, vlin, ctx);
    gemm128<<<gQKV, blk, 0, stream>>>(ctx, WoT, bo, x, x1, ROWS, D_MODEL, D_MODEL, 0, 1);
    ln_kernel<<<ROWS, blk, 0, stream>>>(x1, g2, b2, hln);
    convT_kernel<<<gConv1, blk, 0, stream>>>(W1, W1T, D_MODEL, HID);
    convT_kernel<<<gConv2, blk, 0, stream>>>(W2, W2T, HID, D_MODEL);
    dim3 gW1(ROWS / 128, HID / 128);         // 32x32
    dim3 gW2(ROWS / 128, D_MODEL / 128);     // 32x8
    gemm128<<<gW1, blk, 0, stream>>>(hln, W1T, bm1, nullptr, hmlp, ROWS, HID, D_MODEL, 1, 0);
    gemm128<<<gW2, blk, 0, stream>>>(hmlp, W2T, bm2, x1, out, ROWS, D_MODEL, HID, 0, 1);
  } else {
    // ---------- 32 MB fallback: chunked MLP, d_out doubles as scratch ----------
    __bf16* hln  = (__bf16*)(w + 0 * MB);    // later hln2
    __bf16* vlin = (__bf16*)(w + 8 * MB);    // later W1T
    __bf16* WqT  = (__bf16*)(w + 16 * MB);
    __bf16* WkT  = (__bf16*)(w + 18 * MB);
    __bf16* WvT  = (__bf16*)(w + 20 * MB);
    __bf16* ctx  = (__bf16*)(w + 16 * MB);   // after QKV weights die
    __bf16* hmlp = (__bf16*)(w + 16 * MB);   // after ctx dies
    __bf16* WoT  = (__bf16*)(w + 24 * MB);
    __bf16* W2T  = (__bf16*)(w + 24 * MB);   // after WoT dies
    __bf16* W1T  = vlin;                     // after vlin dies
    __bf16* qlin = (__bf16*)d_out;           // d_out[0,8) MB
    __bf16* klin = (__bf16*)d_out + (size_t)ROWS * D_MODEL;  // d_out[8,16) MB
    float*  x1   = (float*)d_out;            // after q/k die; in-place w/ out

    convT_kernel<<<gConvD, blk, 0, stream>>>(Wq, WqT, D_MODEL, D_MODEL);
    convT_kernel<<<gConvD, blk, 0, stream>>>(Wk, WkT, D_MODEL, D_MODEL);
    convT_kernel<<<gConvD, blk, 0, stream>>>(Wv, WvT, D_MODEL, D_MODEL);
    ln_kernel<<<ROWS, blk, 0, stream>>>(x, g1, b1, hln);
    gemm128<<<gQKV, blk, 0, stream>>>(hln, WqT, bq, nullptr, qlin, ROWS, D_MODEL, D_MODEL, 0, 0);
    gemm128<<<gQKV, blk, 0, stream>>>(hln, WkT, bk, nullptr, klin, ROWS, D_MODEL, D_MODEL, 0, 0);
    gemm128<<<gQKV, blk, 0, stream>>>(hln, WvT, bv, nullptr, vlin, ROWS, D_MODEL, D_MODEL, 0, 0);
    rope_inplace<<<ROWS, blk, 0, stream>>>(qlin, klin, pos);
    attn_kernel<<<BATCH * NH * (SEQ / 64), blk, 0, stream>>>(qlin, klin, vlin, ctx);
    convT_kernel<<<gConvD, blk, 0, stream>>>(Wo, WoT, D_MODEL, D_MODEL);
    gemm128<<<gQKV, blk, 0, stream>>>(ctx, WoT, bo, x, x1, ROWS, D_MODEL, D_MODEL, 0, 1);
    ln_kernel<<<ROWS, blk, 0, stream>>>(x1, g2, b2, hln);
    convT_kernel<<<gConv1, blk, 0, stream>>>(W1, W1T, D_MODEL, HID);
    convT_kernel<<<gConv2, blk, 0, stream>>>(W2, W2T, HID, D_MODEL);
    const int CH = 1024;
    dim3 gW1(CH / 128, HID / 128);           // 8x32
    dim3 gW2(CH / 128, D_MODEL / 128);       // 8x8
    for (int c = 0; c < ROWS / CH; ++c) {
      const __bf16* a1 = hln + (size_t)c * CH * D_MODEL;
      gemm128<<<gW1, blk, 0, stream>>>(a1, W1T, bm1, nullptr, hmlp, CH, HID, D_MODEL, 1, 0);
      gemm128<<<gW2, blk, 0, stream>>>(hmlp, W2T, bm2, x1 + (size_t)c * CH * D_MODEL,
                                       out + (size_t)c * CH * D_MODEL, CH, D_MODEL, HID, 0, 1);
    }
  }
}

// Round 5
// 668.768 us; speedup vs baseline: 1.6973x; 1.2006x over previous
//
#include <hip/hip_runtime.h>

typedef __bf16 bf16x8 __attribute__((ext_vector_type(8)));
typedef __bf16 bf16x4 __attribute__((ext_vector_type(4)));
typedef float  f32x4  __attribute__((ext_vector_type(4)));

#define D_MODEL 1024
#define SEQ     2048
#define BATCH   2
#define NH      16
#define DH      64
#define HID     4096
#define ROWS    (BATCH*SEQ)

static __device__ __forceinline__ void gl_lds16(const __bf16* g, __bf16* l) {
  __builtin_amdgcn_global_load_lds(
      (const __attribute__((address_space(1))) unsigned int*)g,
      (__attribute__((address_space(3))) unsigned int*)l, 16, 0, 0);
}

// ------------------------------------------- LayerNorm: fp32 in, bf16 out
__global__ __launch_bounds__(256) void ln_kernel(
    const float* __restrict__ x, const float* __restrict__ g,
    const float* __restrict__ b, __bf16* __restrict__ out)
{
  int row = blockIdx.x;
  const float* xr = x + (size_t)row * D_MODEL;
  int i0 = threadIdx.x * 4;
  f32x4 xv = *(const f32x4*)(xr + i0);
  float s  = xv[0] + xv[1] + xv[2] + xv[3];
  float ss = xv[0]*xv[0] + xv[1]*xv[1] + xv[2]*xv[2] + xv[3]*xv[3];
#pragma unroll
  for (int off = 1; off < 64; off <<= 1) {
    s  += __shfl_xor(s,  off, 64);
    ss += __shfl_xor(ss, off, 64);
  }
  __shared__ float red[8];
  int wave = threadIdx.x >> 6;
  if ((threadIdx.x & 63) == 0) { red[wave] = s; red[4 + wave] = ss; }
  __syncthreads();
  s  = red[0] + red[1] + red[2] + red[3];
  ss = red[4] + red[5] + red[6] + red[7];
  float mu  = s * (1.0f / D_MODEL);
  float var = ss * (1.0f / D_MODEL) - mu * mu;
  float inv = rsqrtf(var + 1e-5f);
  f32x4 gv = *(const f32x4*)(g + i0);
  f32x4 bv = *(const f32x4*)(b + i0);
  bf16x4 ov;
#pragma unroll
  for (int j = 0; j < 4; ++j)
    ov[j] = (__bf16)((xv[j] - mu) * inv * gv[j] + bv[j]);
  *(bf16x4*)(out + (size_t)row * D_MODEL + i0) = ov;
}

// ---------------------- Weight convert+transpose: fp32 [K][N] -> bf16 [N][K]
__global__ __launch_bounds__(256) void convT_kernel(
    const float* __restrict__ W, __bf16* __restrict__ Wt, int K, int N)
{
  __shared__ float T[32][33];
  int n0 = blockIdx.x * 32, k0 = blockIdx.y * 32;
  int r  = threadIdx.x >> 3;
  int c4 = (threadIdx.x & 7) * 4;
  f32x4 v = *(const f32x4*)(W + (size_t)(k0 + r) * N + n0 + c4);
#pragma unroll
  for (int i = 0; i < 4; ++i) T[r][c4 + i] = v[i];
  __syncthreads();
  bf16x4 o;
#pragma unroll
  for (int i = 0; i < 4; ++i) o[i] = (__bf16)T[c4 + i][r];
  *(bf16x4*)(Wt + (size_t)(n0 + r) * K + k0 + c4) = o;
}

// ------------------------------- Bias concat: [bq | bk | bv] -> bqkv (fp32)
__global__ void biascat_kernel(const float* __restrict__ a,
                               const float* __restrict__ b,
                               const float* __restrict__ c,
                               float* __restrict__ o)
{
  int i = blockIdx.x * 256 + threadIdx.x;
  o[i] = i < 1024 ? a[i] : (i < 2048 ? b[i - 1024] : c[i - 2048]);
}

// ------------------------------------------------- m97-style 128x128 GEMM
__global__ __launch_bounds__(256) void gemm128(
    const __bf16* __restrict__ A, const __bf16* __restrict__ Bt,
    const float* __restrict__ bias, const float* __restrict__ resid,
    void* __restrict__ Cv, int M, int N, int K, int act, int c_fp32)
{
  __shared__ __bf16 As[128 * 32];
  __shared__ __bf16 Bs[128 * 32];
  int tid = threadIdx.x, lane = tid & 63, wv = tid >> 6;
  int quad = lane >> 4, l16 = lane & 15;
  int wr = wv >> 1, wc = wv & 1;
  int row0 = blockIdx.x * 128, col0 = blockIdx.y * 128;
  int srow = lane >> 2, skseg = (lane & 3) * 8;
  f32x4 acc[4][4] = {};

  for (int k0 = 0; k0 < K; k0 += 32) {
#pragma unroll
    for (int q = 0; q < 2; ++q) {
      int c = q * 4 + wv;
      int r = c * 16 + srow;
      gl_lds16(A  + (size_t)(row0 + r) * K + k0 + skseg, As + c * 512);
      gl_lds16(Bt + (size_t)(col0 + r) * K + k0 + skseg, Bs + c * 512);
    }
    __syncthreads();
    bf16x8 af[4], bf[4];
#pragma unroll
    for (int i = 0; i < 4; ++i) {
      af[i] = *(const bf16x8*)(As + (wr * 64 + i * 16 + l16) * 32 + quad * 8);
      bf[i] = *(const bf16x8*)(Bs + (wc * 64 + i * 16 + l16) * 32 + quad * 8);
    }
#pragma unroll
    for (int i = 0; i < 4; ++i)
#pragma unroll
      for (int j = 0; j < 4; ++j)
        acc[i][j] = __builtin_amdgcn_mfma_f32_16x16x32_bf16(af[i], bf[j], acc[i][j], 0, 0, 0);
    __syncthreads();
  }
#pragma unroll
  for (int i = 0; i < 4; ++i) {
    int grow = row0 + wr * 64 + i * 16 + quad * 4;
#pragma unroll
    for (int j = 0; j < 4; ++j) {
      int gcol = col0 + wc * 64 + j * 16 + l16;
      float bsv = bias[gcol];
#pragma unroll
      for (int r = 0; r < 4; ++r) {
        size_t off = (size_t)(grow + r) * N + gcol;
        float v = acc[i][j][r] + bsv;
        if (act) v = 0.5f * v * (1.0f + erff(v * 0.70710678118654752f));
        if (resid) v += resid[off];
        if (c_fp32) ((float*)Cv)[off] = v;
        else        ((__bf16*)Cv)[off] = (__bf16)v;
      }
    }
  }
}

// -------------------------------------- 64x128-tile GEMM (for N=1024 outputs)
__global__ __launch_bounds__(256) void gemm64x128(
    const __bf16* __restrict__ A, const __bf16* __restrict__ Bt,
    const float* __restrict__ bias, const float* __restrict__ resid,
    void* __restrict__ Cv, int M, int N, int K, int act, int c_fp32)
{
  __shared__ __bf16 As[64 * 32];
  __shared__ __bf16 Bs[128 * 32];
  int tid = threadIdx.x, lane = tid & 63, wv = tid >> 6;
  int quad = lane >> 4, l16 = lane & 15;
  int wr = wv >> 1, wc = wv & 1;   // 2x2 waves: 32 rows x 64 cols each
  int row0 = blockIdx.x * 64, col0 = blockIdx.y * 128;
  int srow = lane >> 2, skseg = (lane & 3) * 8;
  f32x4 acc[2][4] = {};

  for (int k0 = 0; k0 < K; k0 += 32) {
    {
      int r = wv * 16 + srow;
      gl_lds16(A + (size_t)(row0 + r) * K + k0 + skseg, As + wv * 512);
    }
#pragma unroll
    for (int q = 0; q < 2; ++q) {
      int c = q * 4 + wv;
      int r = c * 16 + srow;
      gl_lds16(Bt + (size_t)(col0 + r) * K + k0 + skseg, Bs + c * 512);
    }
    __syncthreads();
    bf16x8 af[2], bf[4];
#pragma unroll
    for (int i = 0; i < 2; ++i)
      af[i] = *(const bf16x8*)(As + (wr * 32 + i * 16 + l16) * 32 + quad * 8);
#pragma unroll
    for (int j = 0; j < 4; ++j)
      bf[j] = *(const bf16x8*)(Bs + (wc * 64 + j * 16 + l16) * 32 + quad * 8);
#pragma unroll
    for (int i = 0; i < 2; ++i)
#pragma unroll
      for (int j = 0; j < 4; ++j)
        acc[i][j] = __builtin_amdgcn_mfma_f32_16x16x32_bf16(af[i], bf[j], acc[i][j], 0, 0, 0);
    __syncthreads();
  }
#pragma unroll
  for (int i = 0; i < 2; ++i) {
    int grow = row0 + wr * 32 + i * 16 + quad * 4;
#pragma unroll
    for (int j = 0; j < 4; ++j) {
      int gcol = col0 + wc * 64 + j * 16 + l16;
      float bsv = bias[gcol];
#pragma unroll
      for (int r = 0; r < 4; ++r) {
        size_t off = (size_t)(grow + r) * N + gcol;
        float v = acc[i][j][r] + bsv;
        if (act) v = 0.5f * v * (1.0f + erff(v * 0.70710678118654752f));
        if (resid) v += resid[off];
        if (c_fp32) ((float*)Cv)[off] = v;
        else        ((__bf16*)Cv)[off] = (__bf16)v;
      }
    }
  }
}

// ---------------------------------------------- RoPE (full-D pairs), in place
__global__ __launch_bounds__(256) void rope_inplace(
    __bf16* __restrict__ ql, __bf16* __restrict__ kl,
    const int* __restrict__ pos, int stride)
{
  int row = blockIdx.x;
  int n = row & (SEQ - 1);
  float p = (float)pos[n];
  const size_t rbase = (size_t)row * stride;
#pragma unroll
  for (int t = 0; t < 2; ++t) {
    int i = threadIdx.x + t * 256;
    float fr  = expf(-9.210340371976184f * ((float)i * (1.0f / 512.0f)));
    float ang = p * fr;
    float sn, c;
    sincosf(ang, &sn, &c);
    float q1 = (float)ql[rbase + i], q2 = (float)ql[rbase + 512 + i];
    float k1 = (float)kl[rbase + i], k2 = (float)kl[rbase + 512 + i];
    ql[rbase + i]       = (__bf16)(q1 * c - q2 * sn);
    ql[rbase + 512 + i] = (__bf16)(q1 * sn + q2 * c);
    kl[rbase + i]       = (__bf16)(k1 * c - k2 * sn);
    kl[rbase + 512 + i] = (__bf16)(k1 * sn + k2 * c);
  }
}

// --------------------- V transpose: [B,SEQ,stride] head-cols -> Vt[bh][64][SEQ]
__global__ __launch_bounds__(256) void vtrans_kernel(
    const __bf16* __restrict__ Vsrc, int vstride, __bf16* __restrict__ Vt)
{
  __shared__ __bf16 T[64][72];
  int bh = blockIdx.x;            // b*NH + h
  int kb = blockIdx.y * 64;
  int b = bh >> 4, h = bh & 15;
  int tid = threadIdx.x;
#pragma unroll
  for (int t = 0; t < 2; ++t) {
    int u = tid + t * 256;
    int r = u >> 3, seg = (u & 7) * 8;
    bf16x8 v = *(const bf16x8*)(Vsrc + (size_t)(b * SEQ + kb + r) * vstride + h * DH + seg);
    *(bf16x8*)(&T[r][seg]) = v;
  }
  __syncthreads();
#pragma unroll
  for (int t = 0; t < 2; ++t) {
    int u = tid + t * 256;
    int d = u >> 3, ks = (u & 7) * 8;
    bf16x8 o;
#pragma unroll
    for (int i = 0; i < 8; ++i) o[i] = T[ks + i][d];
    *(bf16x8*)(Vt + ((size_t)bh * DH + d) * SEQ + kb + ks) = o;
  }
}

// --------------------------------------------------- Flash attention (fwd)
// One wave = 16 queries, 128-key tiles, NO barriers (waves independent).
// Interleaved key mapping: score sub-tile j covers key = l16*8 + j, so
// each P row is one contiguous ds_write_b128 per lane.
#define KS 136
__global__ __launch_bounds__(256) void attn_kernel(
    const __bf16* __restrict__ Q, const __bf16* __restrict__ K,
    const __bf16* __restrict__ Vt, __bf16* __restrict__ ctx, int qkstride)
{
  __shared__ __bf16 Pl[4][16 * KS];
  int tid = threadIdx.x, lane = tid & 63, wave = tid >> 6;
  int quad = lane >> 4, l16 = lane & 15;
  int blk = blockIdx.x;
  int q64 = blk & 31;
  int bh  = blk >> 5;
  int b = bh >> 4, h = bh & 15;
  int q0 = q64 * 64 + wave * 16;
  const __bf16* qbase = Q + (size_t)b * SEQ * qkstride + h * DH;
  const __bf16* kbase = K + (size_t)b * SEQ * qkstride + h * DH;
  const __bf16* vbase = Vt + (size_t)bh * DH * SEQ;
  const __bf16* qp = qbase + (size_t)(q0 + l16) * qkstride + quad * 8;
  bf16x8 qf0 = *(const bf16x8*)(qp);
  bf16x8 qf1 = *(const bf16x8*)(qp + 32);
  float mrow[4] = {-1e30f, -1e30f, -1e30f, -1e30f};
  float lrow[4] = {0.f, 0.f, 0.f, 0.f};
  f32x4 acc[4] = {};
  __bf16* pw = &Pl[wave][0];

  for (int kb = 0; kb < SEQ; kb += 128) {
    f32x4 s[8];
#pragma unroll
    for (int j = 0; j < 8; ++j) {
      const __bf16* kp = kbase + (size_t)(kb + l16 * 8 + j) * qkstride + quad * 8;
      bf16x8 kf0 = *(const bf16x8*)(kp);
      bf16x8 kf1 = *(const bf16x8*)(kp + 32);
      f32x4 z = {};
      z = __builtin_amdgcn_mfma_f32_16x16x32_bf16(qf0, kf0, z, 0, 0, 0);
      z = __builtin_amdgcn_mfma_f32_16x16x32_bf16(qf1, kf1, z, 0, 0, 0);
#pragma unroll
      for (int r = 0; r < 4; ++r) s[j][r] = z[r] * 0.125f;   // 1/sqrt(64)
    }
#pragma unroll
    for (int r = 0; r < 4; ++r) {
      float mx = s[0][r];
#pragma unroll
      for (int j = 1; j < 8; ++j) mx = fmaxf(mx, s[j][r]);
#pragma unroll
      for (int off = 1; off < 16; off <<= 1) mx = fmaxf(mx, __shfl_xor(mx, off, 64));
      float mn = fmaxf(mrow[r], mx);
      float al = __expf(mrow[r] - mn);
      float p[8], rs = 0.f;
#pragma unroll
      for (int j = 0; j < 8; ++j) { p[j] = __expf(s[j][r] - mn); rs += p[j]; }
#pragma unroll
      for (int off = 1; off < 16; off <<= 1) rs += __shfl_xor(rs, off, 64);
      lrow[r] = lrow[r] * al + rs;
      mrow[r] = mn;
#pragma unroll
      for (int j = 0; j < 4; ++j) acc[j][r] *= al;
      bf16x8 pv;
#pragma unroll
      for (int j = 0; j < 8; ++j) pv[j] = (__bf16)p[j];
      *(bf16x8*)(pw + (quad * 4 + r) * KS + l16 * 8) = pv;   // keys l16*8..+7
    }
    // PV: P rows per-wave in LDS (lgkmcnt-ordered, no barrier), V from Vt.
#pragma unroll
    for (int kk = 0; kk < 4; ++kk) {
      bf16x8 pf = *(const bf16x8*)(pw + l16 * KS + kk * 32 + quad * 8);
#pragma unroll
      for (int j = 0; j < 4; ++j) {
        bf16x8 vf = *(const bf16x8*)(vbase + (size_t)(j * 16 + l16) * SEQ + kb + kk * 32 + quad * 8);
        acc[j] = __builtin_amdgcn_mfma_f32_16x16x32_bf16(pf, vf, acc[j], 0, 0, 0);
      }
    }
  }
#pragma unroll
  for (int r = 0; r < 4; ++r) {
    int row = q0 + quad * 4 + r;
    float inv = 1.0f / lrow[r];
    size_t obase = ((size_t)(b * SEQ) + row) * D_MODEL + h * DH;
#pragma unroll
    for (int j = 0; j < 4; ++j)
      ctx[obase + j * 16 + l16] = (__bf16)(acc[j][r] * inv);
  }
}

// ------------------------------------------------------------------ launcher
extern "C" void kernel_launch(void* const* d_in, const int* in_sizes, int n_in,
                              void* d_out, int out_size, void* d_ws, size_t ws_size,
                              hipStream_t stream)
{
  const float* x   = (const float*)d_in[0];
  const int*   pos = (const int*)  d_in[1];
  const float* Wq  = (const float*)d_in[2];
  const float* bq  = (const float*)d_in[3];
  const float* Wk  = (const float*)d_in[4];
  const float* bk  = (const float*)d_in[5];
  const float* Wv  = (const float*)d_in[6];
  const float* bv  = (const float*)d_in[7];
  const float* Wo  = (const float*)d_in[8];
  const float* bo  = (const float*)d_in[9];
  const float* g1  = (const float*)d_in[10];
  const float* b1  = (const float*)d_in[11];
  const float* g2  = (const float*)d_in[12];
  const float* b2  = (const float*)d_in[13];
  const float* W1  = (const float*)d_in[14];
  const float* bm1 = (const float*)d_in[15];
  const float* W2  = (const float*)d_in[16];
  const float* bm2 = (const float*)d_in[17];
  float* out = (float*)d_out;

  const size_t MB = 1024 * 1024;
  char* w = (char*)d_ws;
  dim3 blk(256);
  dim3 gConvD(D_MODEL / 32, D_MODEL / 32);
  dim3 gConv1(HID / 32, D_MODEL / 32);
  dim3 gConv2(D_MODEL / 32, HID / 32);
  dim3 gVt(BATCH * NH, SEQ / 64);
  int  gAttn = BATCH * NH * (SEQ / 64);

  if (ws_size >= (size_t)96 * MB) {
    // ---------------- large path (88 MB) ----------------
    __bf16* qkv  = (__bf16*)(w + 0 * MB);    // [4096][3072], 24 MB
    __bf16* Vt   = (__bf16*)(w + 24 * MB);   // [32][64][2048], 8 MB
    __bf16* ctx  = (__bf16*)(w + 32 * MB);   // 8 MB
    float*  x1   = (float*) (w + 40 * MB);   // 16 MB
    __bf16* hln  = (__bf16*)(w + 56 * MB);   // 8 MB
    __bf16* WqkvT= (__bf16*)(w + 64 * MB);   // [3072][1024], 6 MB
    __bf16* WoT  = (__bf16*)(w + 70 * MB);   // 2 MB
    __bf16* W1T  = (__bf16*)(w + 72 * MB);   // 8 MB
    __bf16* W2T  = (__bf16*)(w + 80 * MB);   // 8 MB
    float*  bqkv = (float*) (w + 88 * MB);   // 12 KB
    __bf16* hmlp = qkv;                      // 32 MB reuse (qkv+Vt dead)

    convT_kernel<<<gConvD, blk, 0, stream>>>(Wq, WqkvT,                  D_MODEL, D_MODEL);
    convT_kernel<<<gConvD, blk, 0, stream>>>(Wk, WqkvT + 1024 * 1024,    D_MODEL, D_MODEL);
    convT_kernel<<<gConvD, blk, 0, stream>>>(Wv, WqkvT + 2048 * 1024,    D_MODEL, D_MODEL);
    convT_kernel<<<gConvD, blk, 0, stream>>>(Wo, WoT, D_MODEL, D_MODEL);
    biascat_kernel<<<12, blk, 0, stream>>>(bq, bk, bv, bqkv);
    ln_kernel<<<ROWS, blk, 0, stream>>>(x, g1, b1, hln);
    dim3 gQKV(ROWS / 128, 3072 / 128);       // 32 x 24 = 768 blocks
    gemm128<<<gQKV, blk, 0, stream>>>(hln, WqkvT, bqkv, nullptr, qkv, ROWS, 3072, D_MODEL, 0, 0);
    rope_inplace<<<ROWS, blk, 0, stream>>>(qkv, qkv + 1024, pos, 3072);
    vtrans_kernel<<<gVt, blk, 0, stream>>>(qkv + 2048, 3072, Vt);
    attn_kernel<<<gAttn, blk, 0, stream>>>(qkv, qkv + 1024, Vt, ctx, 3072);
    dim3 gWo(ROWS / 64, D_MODEL / 128);      // 64 x 8 = 512 blocks
    gemm64x128<<<gWo, blk, 0, stream>>>(ctx, WoT, bo, x, x1, ROWS, D_MODEL, D_MODEL, 0, 1);
    ln_kernel<<<ROWS, blk, 0, stream>>>(x1, g2, b2, hln);
    convT_kernel<<<gConv1, blk, 0, stream>>>(W1, W1T, D_MODEL, HID);
    convT_kernel<<<gConv2, blk, 0, stream>>>(W2, W2T, HID, D_MODEL);
    dim3 gW1(ROWS / 128, HID / 128);         // 32 x 32 = 1024 blocks
    gemm128<<<gW1, blk, 0, stream>>>(hln, W1T, bm1, nullptr, hmlp, ROWS, HID, D_MODEL, 1, 0);
    dim3 gW2(ROWS / 64, D_MODEL / 128);      // 64 x 8 = 512 blocks
    gemm64x128<<<gW2, blk, 0, stream>>>(hmlp, W2T, bm2, x1, out, ROWS, D_MODEL, HID, 0, 1);
  } else {
    // ---------------- 32 MB fallback (d_out doubles as scratch) ----------------
    __bf16* hln  = (__bf16*)(w + 0 * MB);    // ln1 out, later ln2 out
    __bf16* vlin = (__bf16*)(w + 8 * MB);    // v linear
    __bf16* WqT  = (__bf16*)(w + 16 * MB);
    __bf16* WkT  = (__bf16*)(w + 18 * MB);
    __bf16* WvT  = (__bf16*)(w + 20 * MB);
    __bf16* ctx  = (__bf16*)(w + 16 * MB);   // after QKV weights die
    __bf16* WoT  = (__bf16*)(w + 8 * MB);    // after vlin dies (post-vtrans)
    __bf16* W1T  = (__bf16*)(w + 8 * MB);    // after WoT dies
    __bf16* W2T  = (__bf16*)(w + 16 * MB);   // after ctx dies
    __bf16* Vt   = (__bf16*)(w + 24 * MB);   // 8 MB
    __bf16* hmlp = (__bf16*)(w + 24 * MB);   // after Vt dies
    __bf16* qlin = (__bf16*)d_out;
    __bf16* klin = (__bf16*)d_out + (size_t)ROWS * D_MODEL;
    float*  x1   = (float*)d_out;            // after q/k die

    convT_kernel<<<gConvD, blk, 0, stream>>>(Wq, WqT, D_MODEL, D_MODEL);
    convT_kernel<<<gConvD, blk, 0, stream>>>(Wk, WkT, D_MODEL, D_MODEL);
    convT_kernel<<<gConvD, blk, 0, stream>>>(Wv, WvT, D_MODEL, D_MODEL);
    ln_kernel<<<ROWS, blk, 0, stream>>>(x, g1, b1, hln);
    dim3 gLin(ROWS / 64, D_MODEL / 128);     // 64 x 8 = 512 blocks
    gemm64x128<<<gLin, blk, 0, stream>>>(hln, WqT, bq, nullptr, qlin, ROWS, D_MODEL, D_MODEL, 0, 0);
    gemm64x128<<<gLin, blk, 0, stream>>>(hln, WkT, bk, nullptr, klin, ROWS, D_MODEL, D_MODEL, 0, 0);
    gemm64x128<<<gLin, blk, 0, stream>>>(hln, WvT, bv, nullptr, vlin, ROWS, D_MODEL, D_MODEL, 0, 0);
    rope_inplace<<<ROWS, blk, 0, stream>>>(qlin, klin, pos, D_MODEL);
    vtrans_kernel<<<gVt, blk, 0, stream>>>(vlin, D_MODEL, Vt);
    attn_kernel<<<gAttn, blk, 0, stream>>>(qlin, klin, Vt, ctx, D_MODEL);
    convT_kernel<<<gConvD, blk, 0, stream>>>(Wo, WoT, D_MODEL, D_MODEL);
    gemm64x128<<<gLin, blk, 0, stream>>>(ctx, WoT, bo, x, x1, ROWS, D_MODEL, D_MODEL, 0, 1);
    ln_kernel<<<ROWS, blk, 0, stream>>>(x1, g2, b2, hln);
    convT_kernel<<<gConv1, blk, 0, stream>>>(W1, W1T, D_MODEL, HID);
    convT_kernel<<<gConv2, blk, 0, stream>>>(W2, W2T, HID, D_MODEL);
    const int CH = 1024;
    dim3 gC1(CH / 128, HID / 128);           // 8 x 32 = 256 blocks
    dim3 gC2(CH / 64, D_MODEL / 128);        // 16 x 8 = 128 blocks
    for (int c = 0; c < ROWS / CH; ++c) {
      const __bf16* a1 = hln + (size_t)c * CH * D_MODEL;
      gemm128<<<gC1, blk, 0, stream>>>(a1, W1T, bm1, nullptr, hmlp, CH, HID, D_MODEL, 1, 0);
      gemm64x128<<<gC2, blk, 0, stream>>>(hmlp, W2T, bm2, x1 + (size_t)c * CH * D_MODEL,
                                          out + (size_t)c * CH * D_MODEL, CH, D_MODEL, HID, 0, 1);
    }
  }
}

// Round 6
// 621.005 us; speedup vs baseline: 1.8278x; 1.0769x over previous
//
#include <hip/hip_runtime.h>

typedef __bf16 bf16x8 __attribute__((ext_vector_type(8)));
typedef __bf16 bf16x4 __attribute__((ext_vector_type(4)));
typedef float  f32x4  __attribute__((ext_vector_type(4)));

#define D_MODEL 1024
#define SEQ     2048
#define BATCH   2
#define NH      16
#define DH      64
#define HID     4096
#define ROWS    (BATCH*SEQ)

static __device__ __forceinline__ void gl_lds16(const __bf16* g, __bf16* l) {
  __builtin_amdgcn_global_load_lds(
      (const __attribute__((address_space(1))) unsigned int*)g,
      (__attribute__((address_space(3))) unsigned int*)l, 16, 0, 0);
}

// ------------------------------------------- LayerNorm: fp32 in, bf16 out
__global__ __launch_bounds__(256) void ln_kernel(
    const float* __restrict__ x, const float* __restrict__ g,
    const float* __restrict__ b, __bf16* __restrict__ out)
{
  int row = blockIdx.x;
  const float* xr = x + (size_t)row * D_MODEL;
  int i0 = threadIdx.x * 4;
  f32x4 xv = *(const f32x4*)(xr + i0);
  float s  = xv[0] + xv[1] + xv[2] + xv[3];
  float ss = xv[0]*xv[0] + xv[1]*xv[1] + xv[2]*xv[2] + xv[3]*xv[3];
#pragma unroll
  for (int off = 1; off < 64; off <<= 1) {
    s  += __shfl_xor(s,  off, 64);
    ss += __shfl_xor(ss, off, 64);
  }
  __shared__ float red[8];
  int wave = threadIdx.x >> 6;
  if ((threadIdx.x & 63) == 0) { red[wave] = s; red[4 + wave] = ss; }
  __syncthreads();
  s  = red[0] + red[1] + red[2] + red[3];
  ss = red[4] + red[5] + red[6] + red[7];
  float mu  = s * (1.0f / D_MODEL);
  float var = ss * (1.0f / D_MODEL) - mu * mu;
  float inv = rsqrtf(var + 1e-5f);
  f32x4 gv = *(const f32x4*)(g + i0);
  f32x4 bv = *(const f32x4*)(b + i0);
  bf16x4 ov;
#pragma unroll
  for (int j = 0; j < 4; ++j)
    ov[j] = (__bf16)((xv[j] - mu) * inv * gv[j] + bv[j]);
  *(bf16x4*)(out + (size_t)row * D_MODEL + i0) = ov;
}

// ---------------------- Weight convert+transpose: fp32 [K][N] -> bf16 [N][K]
__global__ __launch_bounds__(256) void convT_kernel(
    const float* __restrict__ W, __bf16* __restrict__ Wt, int K, int N)
{
  __shared__ float T[32][33];
  int n0 = blockIdx.x * 32, k0 = blockIdx.y * 32;
  int r  = threadIdx.x >> 3;
  int c4 = (threadIdx.x & 7) * 4;
  f32x4 v = *(const f32x4*)(W + (size_t)(k0 + r) * N + n0 + c4);
#pragma unroll
  for (int i = 0; i < 4; ++i) T[r][c4 + i] = v[i];
  __syncthreads();
  bf16x4 o;
#pragma unroll
  for (int i = 0; i < 4; ++i) o[i] = (__bf16)T[c4 + i][r];
  *(bf16x4*)(Wt + (size_t)(n0 + r) * K + k0 + c4) = o;
}

// ------------------------------- Bias concat: [bq | bk | bv] -> bqkv (fp32)
__global__ void biascat_kernel(const float* __restrict__ a,
                               const float* __restrict__ b,
                               const float* __restrict__ c,
                               float* __restrict__ o)
{
  int i = blockIdx.x * 256 + threadIdx.x;
  o[i] = i < 1024 ? a[i] : (i < 2048 ? b[i - 1024] : c[i - 2048]);
}

// ------------------------------------------------- m97-style 128x128 GEMM
__global__ __launch_bounds__(256) void gemm128(
    const __bf16* __restrict__ A, const __bf16* __restrict__ Bt,
    const float* __restrict__ bias, const float* __restrict__ resid,
    void* __restrict__ Cv, int M, int N, int K, int act, int c_fp32)
{
  __shared__ __bf16 As[128 * 32];
  __shared__ __bf16 Bs[128 * 32];
  int tid = threadIdx.x, lane = tid & 63, wv = tid >> 6;
  int quad = lane >> 4, l16 = lane & 15;
  int wr = wv >> 1, wc = wv & 1;
  int row0 = blockIdx.x * 128, col0 = blockIdx.y * 128;
  int srow = lane >> 2, skseg = (lane & 3) * 8;
  f32x4 acc[4][4] = {};

  for (int k0 = 0; k0 < K; k0 += 32) {
#pragma unroll
    for (int q = 0; q < 2; ++q) {
      int c = q * 4 + wv;
      int r = c * 16 + srow;
      gl_lds16(A  + (size_t)(row0 + r) * K + k0 + skseg, As + c * 512);
      gl_lds16(Bt + (size_t)(col0 + r) * K + k0 + skseg, Bs + c * 512);
    }
    __syncthreads();
    bf16x8 af[4], bf[4];
#pragma unroll
    for (int i = 0; i < 4; ++i) {
      af[i] = *(const bf16x8*)(As + (wr * 64 + i * 16 + l16) * 32 + quad * 8);
      bf[i] = *(const bf16x8*)(Bs + (wc * 64 + i * 16 + l16) * 32 + quad * 8);
    }
#pragma unroll
    for (int i = 0; i < 4; ++i)
#pragma unroll
      for (int j = 0; j < 4; ++j)
        acc[i][j] = __builtin_amdgcn_mfma_f32_16x16x32_bf16(af[i], bf[j], acc[i][j], 0, 0, 0);
    __syncthreads();
  }
#pragma unroll
  for (int i = 0; i < 4; ++i) {
    int grow = row0 + wr * 64 + i * 16 + quad * 4;
#pragma unroll
    for (int j = 0; j < 4; ++j) {
      int gcol = col0 + wc * 64 + j * 16 + l16;
      float bsv = bias[gcol];
#pragma unroll
      for (int r = 0; r < 4; ++r) {
        size_t off = (size_t)(grow + r) * N + gcol;
        float v = acc[i][j][r] + bsv;
        if (act) v = 0.5f * v * (1.0f + erff(v * 0.70710678118654752f));
        if (resid) v += resid[off];
        if (c_fp32) ((float*)Cv)[off] = v;
        else        ((__bf16*)Cv)[off] = (__bf16)v;
      }
    }
  }
}

// -------------------------------------- 64x128-tile GEMM (for N=1024 outputs)
__global__ __launch_bounds__(256) void gemm64x128(
    const __bf16* __restrict__ A, const __bf16* __restrict__ Bt,
    const float* __restrict__ bias, const float* __restrict__ resid,
    void* __restrict__ Cv, int M, int N, int K, int act, int c_fp32)
{
  __shared__ __bf16 As[64 * 32];
  __shared__ __bf16 Bs[128 * 32];
  int tid = threadIdx.x, lane = tid & 63, wv = tid >> 6;
  int quad = lane >> 4, l16 = lane & 15;
  int wr = wv >> 1, wc = wv & 1;
  int row0 = blockIdx.x * 64, col0 = blockIdx.y * 128;
  int srow = lane >> 2, skseg = (lane & 3) * 8;
  f32x4 acc[2][4] = {};

  for (int k0 = 0; k0 < K; k0 += 32) {
    {
      int r = wv * 16 + srow;
      gl_lds16(A + (size_t)(row0 + r) * K + k0 + skseg, As + wv * 512);
    }
#pragma unroll
    for (int q = 0; q < 2; ++q) {
      int c = q * 4 + wv;
      int r = c * 16 + srow;
      gl_lds16(Bt + (size_t)(col0 + r) * K + k0 + skseg, Bs + c * 512);
    }
    __syncthreads();
    bf16x8 af[2], bf[4];
#pragma unroll
    for (int i = 0; i < 2; ++i)
      af[i] = *(const bf16x8*)(As + (wr * 32 + i * 16 + l16) * 32 + quad * 8);
#pragma unroll
    for (int j = 0; j < 4; ++j)
      bf[j] = *(const bf16x8*)(Bs + (wc * 64 + j * 16 + l16) * 32 + quad * 8);
#pragma unroll
    for (int i = 0; i < 2; ++i)
#pragma unroll
      for (int j = 0; j < 4; ++j)
        acc[i][j] = __builtin_amdgcn_mfma_f32_16x16x32_bf16(af[i], bf[j], acc[i][j], 0, 0, 0);
    __syncthreads();
  }
#pragma unroll
  for (int i = 0; i < 2; ++i) {
    int grow = row0 + wr * 32 + i * 16 + quad * 4;
#pragma unroll
    for (int j = 0; j < 4; ++j) {
      int gcol = col0 + wc * 64 + j * 16 + l16;
      float bsv = bias[gcol];
#pragma unroll
      for (int r = 0; r < 4; ++r) {
        size_t off = (size_t)(grow + r) * N + gcol;
        float v = acc[i][j][r] + bsv;
        if (act) v = 0.5f * v * (1.0f + erff(v * 0.70710678118654752f));
        if (resid) v += resid[off];
        if (c_fp32) ((float*)Cv)[off] = v;
        else        ((__bf16*)Cv)[off] = (__bf16)v;
      }
    }
  }
}

// ------------------------- RoPE + repack qkv -> per-head Qh/Kh [bh][SEQ][64]
__global__ __launch_bounds__(256) void rope_repack(
    const __bf16* __restrict__ qkv, const int* __restrict__ pos,
    __bf16* __restrict__ Qh, __bf16* __restrict__ Kh)
{
  int row = blockIdx.x;
  int b = row >> 11, n = row & (SEQ - 1);
  float p = (float)pos[n];
  const __bf16* qr = qkv + (size_t)row * 3072;
#pragma unroll
  for (int t = 0; t < 2; ++t) {
    int i = threadIdx.x + t * 256;      // 0..511
    float fr  = expf(-9.210340371976184f * ((float)i * (1.0f / 512.0f)));
    float ang = p * fr;
    float sn, c;
    sincosf(ang, &sn, &c);
    float q1 = (float)qr[i],        q2 = (float)qr[512 + i];
    float k1 = (float)qr[1024 + i], k2 = (float)qr[1536 + i];
    int h1 = i >> 6, d1 = i & 63;
    int h2 = (i + 512) >> 6;
    size_t o1 = ((size_t)(b * NH + h1) * SEQ + n) * DH + d1;
    size_t o2 = ((size_t)(b * NH + h2) * SEQ + n) * DH + d1;
    Qh[o1] = (__bf16)(q1 * c - q2 * sn);
    Qh[o2] = (__bf16)(q1 * sn + q2 * c);
    Kh[o1] = (__bf16)(k1 * c - k2 * sn);
    Kh[o2] = (__bf16)(k1 * sn + k2 * c);
  }
}

// ----- V transpose. blocked=0: Vt[bh][64][SEQ]; blocked=1: Vt[bh][seg][64][128]
__global__ __launch_bounds__(256) void vtrans_kernel(
    const __bf16* __restrict__ Vsrc, int vstride, __bf16* __restrict__ Vt,
    int blocked)
{
  __shared__ __bf16 T[64][72];
  int bh = blockIdx.x;
  int kb = blockIdx.y * 64;
  int b = bh >> 4, h = bh & 15;
  int tid = threadIdx.x;
#pragma unroll
  for (int t = 0; t < 2; ++t) {
    int u = tid + t * 256;
    int r = u >> 3, seg = (u & 7) * 8;
    bf16x8 v = *(const bf16x8*)(Vsrc + (size_t)(b * SEQ + kb + r) * vstride + h * DH + seg);
    *(bf16x8*)(&T[r][seg]) = v;
  }
  __syncthreads();
#pragma unroll
  for (int t = 0; t < 2; ++t) {
    int u = tid + t * 256;
    int d = u >> 3, ks = (u & 7) * 8;
    bf16x8 o;
#pragma unroll
    for (int i = 0; i < 8; ++i) o[i] = T[ks + i][d];
    if (blocked) {
      int key = kb + ks;
      *(bf16x8*)(Vt + (((size_t)bh * (SEQ / 128) + (key >> 7)) * DH + d) * 128 + (key & 127)) = o;
    } else {
      *(bf16x8*)(Vt + ((size_t)bh * DH + d) * SEQ + kb + ks) = o;
    }
  }
}

// ------------------- Flash attention, split-K=2, compact layouts, partials
#define KS 136
__global__ __launch_bounds__(256) void attn_split(
    const __bf16* __restrict__ Qh, const __bf16* __restrict__ Kh,
    const __bf16* __restrict__ Vt, __bf16* __restrict__ pacc,
    float* __restrict__ pml)
{
  __shared__ __bf16 Pl[4][16 * KS];
  int tid = threadIdx.x, lane = tid & 63, wave = tid >> 6;
  int quad = lane >> 4, l16 = lane & 15;
  int blk = blockIdx.x;               // ((bh*32 + q64)*2 + split)
  int split = blk & 1;
  int bq = blk >> 1;
  int q64 = bq & 31, bh = bq >> 5;
  int q0 = q64 * 64 + wave * 16;
  const __bf16* qbase = Qh + (size_t)bh * SEQ * DH;
  const __bf16* kbase = Kh + (size_t)bh * SEQ * DH;
  const __bf16* vbase = Vt + (size_t)bh * SEQ * DH;   // blocked layout
  const __bf16* qp = qbase + (size_t)(q0 + l16) * DH + quad * 8;
  bf16x8 qf0 = *(const bf16x8*)(qp);
  bf16x8 qf1 = *(const bf16x8*)(qp + 32);
  float mrow[4] = {-1e30f, -1e30f, -1e30f, -1e30f};
  float lrow[4] = {0.f, 0.f, 0.f, 0.f};
  f32x4 acc[4] = {};
  __bf16* pw = &Pl[wave][0];

  int kb_end = (split + 1) * (SEQ / 2);
  for (int kb = split * (SEQ / 2); kb < kb_end; kb += 128) {
    f32x4 s[8];
#pragma unroll
    for (int j = 0; j < 8; ++j) {
      const __bf16* kp = kbase + (size_t)(kb + l16 * 8 + j) * DH + quad * 8;
      bf16x8 kf0 = *(const bf16x8*)(kp);
      bf16x8 kf1 = *(const bf16x8*)(kp + 32);
      f32x4 z = {};
      z = __builtin_amdgcn_mfma_f32_16x16x32_bf16(qf0, kf0, z, 0, 0, 0);
      z = __builtin_amdgcn_mfma_f32_16x16x32_bf16(qf1, kf1, z, 0, 0, 0);
#pragma unroll
      for (int r = 0; r < 4; ++r) s[j][r] = z[r] * 0.125f;   // 1/sqrt(64)
    }
#pragma unroll
    for (int r = 0; r < 4; ++r) {
      float mx = s[0][r];
#pragma unroll
      for (int j = 1; j < 8; ++j) mx = fmaxf(mx, s[j][r]);
#pragma unroll
      for (int off = 1; off < 16; off <<= 1) mx = fmaxf(mx, __shfl_xor(mx, off, 64));
      float mn = fmaxf(mrow[r], mx);
      float al = __expf(mrow[r] - mn);
      float p[8], rs = 0.f;
#pragma unroll
      for (int j = 0; j < 8; ++j) { p[j] = __expf(s[j][r] - mn); rs += p[j]; }
#pragma unroll
      for (int off = 1; off < 16; off <<= 1) rs += __shfl_xor(rs, off, 64);
      lrow[r] = lrow[r] * al + rs;
      mrow[r] = mn;
#pragma unroll
      for (int j = 0; j < 4; ++j) acc[j][r] *= al;
      bf16x8 pv;
#pragma unroll
      for (int j = 0; j < 8; ++j) pv[j] = (__bf16)p[j];
      *(bf16x8*)(pw + (quad * 4 + r) * KS + l16 * 8) = pv;
    }
    const __bf16* vseg = vbase + (size_t)(kb >> 7) * (DH * 128);
#pragma unroll
    for (int kk = 0; kk < 4; ++kk) {
      bf16x8 pf = *(const bf16x8*)(pw + l16 * KS + kk * 32 + quad * 8);
#pragma unroll
      for (int j = 0; j < 4; ++j) {
        bf16x8 vf = *(const bf16x8*)(vseg + (size_t)(j * 16 + l16) * 128 + kk * 32 + quad * 8);
        acc[j] = __builtin_amdgcn_mfma_f32_16x16x32_bf16(pf, vf, acc[j], 0, 0, 0);
      }
    }
  }
  // partial outputs: unnormalized acc (bf16) + m,l (fp32)
#pragma unroll
  for (int r = 0; r < 4; ++r) {
    int brow = wave * 16 + quad * 4 + r;
#pragma unroll
    for (int j = 0; j < 4; ++j)
      pacc[((size_t)blk * 64 + brow) * 64 + j * 16 + l16] = (__bf16)acc[j][r];
    if (l16 == 0) {
      pml[(size_t)blk * 128 + brow]      = mrow[r];
      pml[(size_t)blk * 128 + 64 + brow] = lrow[r];
    }
  }
}

// ------------------------------------------- combine 2 splits -> ctx (bf16)
__global__ __launch_bounds__(256) void attn_combine(
    const __bf16* __restrict__ pacc, const float* __restrict__ pml,
    __bf16* __restrict__ ctx)
{
  int bq = blockIdx.x;                // bh*32 + q64
  int q64 = bq & 31, bh = bq >> 5;
  int b = bh >> 4, h = bh & 15;
  int tid = threadIdx.x;
  int r = tid >> 2;                   // 0..63
  int c = (tid & 3) * 16;
  int blk0 = bq * 2, blk1 = blk0 + 1;
  float m0 = pml[(size_t)blk0 * 128 + r], l0 = pml[(size_t)blk0 * 128 + 64 + r];
  float m1 = pml[(size_t)blk1 * 128 + r], l1 = pml[(size_t)blk1 * 128 + 64 + r];
  float m = fmaxf(m0, m1);
  float w0 = __expf(m0 - m), w1 = __expf(m1 - m);
  float inv = 1.0f / (w0 * l0 + w1 * l1);
  size_t r0 = ((size_t)blk0 * 64 + r) * 64 + c;
  size_t r1 = ((size_t)blk1 * 64 + r) * 64 + c;
  size_t ob = ((size_t)(b * SEQ) + q64 * 64 + r) * D_MODEL + h * DH + c;
#pragma unroll
  for (int g = 0; g < 2; ++g) {
    bf16x8 a0 = *(const bf16x8*)(pacc + r0 + g * 8);
    bf16x8 a1 = *(const bf16x8*)(pacc + r1 + g * 8);
    bf16x8 o;
#pragma unroll
    for (int i = 0; i < 8; ++i)
      o[i] = (__bf16)((w0 * (float)a0[i] + w1 * (float)a1[i]) * inv);
    *(bf16x8*)(ctx + ob + g * 8) = o;
  }
}

// ------------ legacy kernels for the small-workspace fallback path ------------
__global__ __launch_bounds__(256) void rope_inplace(
    __bf16* __restrict__ ql, __bf16* __restrict__ kl,
    const int* __restrict__ pos, int stride)
{
  int row = blockIdx.x;
  int n = row & (SEQ - 1);
  float p = (float)pos[n];
  const size_t rbase = (size_t)row * stride;
#pragma unroll
  for (int t = 0; t < 2; ++t) {
    int i = threadIdx.x + t * 256;
    float fr  = expf(-9.210340371976184f * ((float)i * (1.0f / 512.0f)));
    float ang = p * fr;
    float sn, c;
    sincosf(ang, &sn, &c);
    float q1 = (float)ql[rbase + i], q2 = (float)ql[rbase + 512 + i];
    float k1 = (float)kl[rbase + i], k2 = (float)kl[rbase + 512 + i];
    ql[rbase + i]       = (__bf16)(q1 * c - q2 * sn);
    ql[rbase + 512 + i] = (__bf16)(q1 * sn + q2 * c);
    kl[rbase + i]       = (__bf16)(k1 * c - k2 * sn);
    kl[rbase + 512 + i] = (__bf16)(k1 * sn + k2 * c);
  }
}

__global__ __launch_bounds__(256) void attn_kernel(
    const __bf16* __restrict__ Q, const __bf16* __restrict__ K,
    const __bf16* __restrict__ Vt, __bf16* __restrict__ ctx, int qkstride)
{
  __shared__ __bf16 Pl[4][16 * KS];
  int tid = threadIdx.x, lane = tid & 63, wave = tid >> 6;
  int quad = lane >> 4, l16 = lane & 15;
  int blk = blockIdx.x;
  int q64 = blk & 31;
  int bh  = blk >> 5;
  int b = bh >> 4, h = bh & 15;
  int q0 = q64 * 64 + wave * 16;
  const __bf16* qbase = Q + (size_t)b * SEQ * qkstride + h * DH;
  const __bf16* kbase = K + (size_t)b * SEQ * qkstride + h * DH;
  const __bf16* vbase = Vt + (size_t)bh * DH * SEQ;
  const __bf16* qp = qbase + (size_t)(q0 + l16) * qkstride + quad * 8;
  bf16x8 qf0 = *(const bf16x8*)(qp);
  bf16x8 qf1 = *(const bf16x8*)(qp + 32);
  float mrow[4] = {-1e30f, -1e30f, -1e30f, -1e30f};
  float lrow[4] = {0.f, 0.f, 0.f, 0.f};
  f32x4 acc[4] = {};
  __bf16* pw = &Pl[wave][0];

  for (int kb = 0; kb < SEQ; kb += 128) {
    f32x4 s[8];
#pragma unroll
    for (int j = 0; j < 8; ++j) {
      const __bf16* kp = kbase + (size_t)(kb + l16 * 8 + j) * qkstride + quad * 8;
      bf16x8 kf0 = *(const bf16x8*)(kp);
      bf16x8 kf1 = *(const bf16x8*)(kp + 32);
      f32x4 z = {};
      z = __builtin_amdgcn_mfma_f32_16x16x32_bf16(qf0, kf0, z, 0, 0, 0);
      z = __builtin_amdgcn_mfma_f32_16x16x32_bf16(qf1, kf1, z, 0, 0, 0);
#pragma unroll
      for (int r = 0; r < 4; ++r) s[j][r] = z[r] * 0.125f;
    }
#pragma unroll
    for (int r = 0; r < 4; ++r) {
      float mx = s[0][r];
#pragma unroll
      for (int j = 1; j < 8; ++j) mx = fmaxf(mx, s[j][r]);
#pragma unroll
      for (int off = 1; off < 16; off <<= 1) mx = fmaxf(mx, __shfl_xor(mx, off, 64));
      float mn = fmaxf(mrow[r], mx);
      float al = __expf(mrow[r] - mn);
      float p[8], rs = 0.f;
#pragma unroll
      for (int j = 0; j < 8; ++j) { p[j] = __expf(s[j][r] - mn); rs += p[j]; }
#pragma unroll
      for (int off = 1; off < 16; off <<= 1) rs += __shfl_xor(rs, off, 64);
      lrow[r] = lrow[r] * al + rs;
      mrow[r] = mn;
#pragma unroll
      for (int j = 0; j < 4; ++j) acc[j][r] *= al;
      bf16x8 pv;
#pragma unroll
      for (int j = 0; j < 8; ++j) pv[j] = (__bf16)p[j];
      *(bf16x8*)(pw + (quad * 4 + r) * KS + l16 * 8) = pv;
    }
#pragma unroll
    for (int kk = 0; kk < 4; ++kk) {
      bf16x8 pf = *(const bf16x8*)(pw + l16 * KS + kk * 32 + quad * 8);
#pragma unroll
      for (int j = 0; j < 4; ++j) {
        bf16x8 vf = *(const bf16x8*)(vbase + (size_t)(j * 16 + l16) * SEQ + kb + kk * 32 + quad * 8);
        acc[j] = __builtin_amdgcn_mfma_f32_16x16x32_bf16(pf, vf, acc[j], 0, 0, 0);
      }
    }
  }
#pragma unroll
  for (int r = 0; r < 4; ++r) {
    int row = q0 + quad * 4 + r;
    float inv = 1.0f / lrow[r];
    size_t obase = ((size_t)(b * SEQ) + row) * D_MODEL + h * DH;
#pragma unroll
    for (int j = 0; j < 4; ++j)
      ctx[obase + j * 16 + l16] = (__bf16)(acc[j][r] * inv);
  }
}

// ------------------------------------------------------------------ launcher
extern "C" void kernel_launch(void* const* d_in, const int* in_sizes, int n_in,
                              void* d_out, int out_size, void* d_ws, size_t ws_size,
                              hipStream_t stream)
{
  const float* x   = (const float*)d_in[0];
  const int*   pos = (const int*)  d_in[1];
  const float* Wq  = (const float*)d_in[2];
  const float* bq  = (const float*)d_in[3];
  const float* Wk  = (const float*)d_in[4];
  const float* bk  = (const float*)d_in[5];
  const float* Wv  = (const float*)d_in[6];
  const float* bv  = (const float*)d_in[7];
  const float* Wo  = (const float*)d_in[8];
  const float* bo  = (const float*)d_in[9];
  const float* g1  = (const float*)d_in[10];
  const float* b1  = (const float*)d_in[11];
  const float* g2  = (const float*)d_in[12];
  const float* b2  = (const float*)d_in[13];
  const float* W1  = (const float*)d_in[14];
  const float* bm1 = (const float*)d_in[15];
  const float* W2  = (const float*)d_in[16];
  const float* bm2 = (const float*)d_in[17];
  float* out = (float*)d_out;

  const size_t MB = 1024 * 1024;
  char* w = (char*)d_ws;
  dim3 blk(256);
  dim3 gConvD(D_MODEL / 32, D_MODEL / 32);
  dim3 gConv1(HID / 32, D_MODEL / 32);
  dim3 gConv2(D_MODEL / 32, HID / 32);
  dim3 gVt(BATCH * NH, SEQ / 64);

  if (ws_size >= (size_t)96 * MB) {
    // ---------------- large path ----------------
    // 0-8: hln | 8-24: x1 (fp32) | 24-48: qkv -> pacc(24-41)+pml(41-42) -> hmlp(24-56)
    // 48-56: Qh -> ctx | 56-64: Kh -> W2T | 64-72: Vt -> W1T
    // 72-78: WqkvT | 78-80: WoT | 80-80.1: bqkv
    __bf16* hln   = (__bf16*)(w + 0 * MB);
    float*  x1    = (float*) (w + 8 * MB);
    __bf16* qkv   = (__bf16*)(w + 24 * MB);
    __bf16* pacc  = (__bf16*)(w + 24 * MB);
    float*  pml   = (float*) (w + 41 * MB);
    __bf16* hmlp  = (__bf16*)(w + 24 * MB);
    __bf16* Qh    = (__bf16*)(w + 48 * MB);
    __bf16* ctx   = (__bf16*)(w + 48 * MB);
    __bf16* Kh    = (__bf16*)(w + 56 * MB);
    __bf16* W2T   = (__bf16*)(w + 56 * MB);
    __bf16* Vt    = (__bf16*)(w + 64 * MB);
    __bf16* W1T   = (__bf16*)(w + 64 * MB);
    __bf16* WqkvT = (__bf16*)(w + 72 * MB);
    __bf16* WoT   = (__bf16*)(w + 78 * MB);
    float*  bqkv  = (float*) (w + 80 * MB);

    convT_kernel<<<gConvD, blk, 0, stream>>>(Wq, WqkvT,               D_MODEL, D_MODEL);
    convT_kernel<<<gConvD, blk, 0, stream>>>(Wk, WqkvT + 1024 * 1024, D_MODEL, D_MODEL);
    convT_kernel<<<gConvD, blk, 0, stream>>>(Wv, WqkvT + 2048 * 1024, D_MODEL, D_MODEL);
    convT_kernel<<<gConvD, blk, 0, stream>>>(Wo, WoT, D_MODEL, D_MODEL);
    biascat_kernel<<<12, blk, 0, stream>>>(bq, bk, bv, bqkv);
    ln_kernel<<<ROWS, blk, 0, stream>>>(x, g1, b1, hln);
    dim3 gQKV(ROWS / 128, 3072 / 128);
    gemm128<<<gQKV, blk, 0, stream>>>(hln, WqkvT, bqkv, nullptr, qkv, ROWS, 3072, D_MODEL, 0, 0);
    rope_repack<<<ROWS, blk, 0, stream>>>(qkv, pos, Qh, Kh);
    vtrans_kernel<<<gVt, blk, 0, stream>>>(qkv + 2048, 3072, Vt, 1);
    attn_split<<<BATCH * NH * (SEQ / 64) * 2, blk, 0, stream>>>(Qh, Kh, Vt, pacc, pml);
    attn_combine<<<BATCH * NH * (SEQ / 64), blk, 0, stream>>>(pacc, pml, ctx);
    convT_kernel<<<gConv1, blk, 0, stream>>>(W1, W1T, D_MODEL, HID);
    convT_kernel<<<gConv2, blk, 0, stream>>>(W2, W2T, HID, D_MODEL);
    dim3 gWo(ROWS / 64, D_MODEL / 128);
    gemm64x128<<<gWo, blk, 0, stream>>>(ctx, WoT, bo, x, x1, ROWS, D_MODEL, D_MODEL, 0, 1);
    ln_kernel<<<ROWS, blk, 0, stream>>>(x1, g2, b2, hln);
    dim3 gW1(ROWS / 128, HID / 128);
    gemm128<<<gW1, blk, 0, stream>>>(hln, W1T, bm1, nullptr, hmlp, ROWS, HID, D_MODEL, 1, 0);
    dim3 gW2(ROWS / 64, D_MODEL / 128);
    gemm64x128<<<gW2, blk, 0, stream>>>(hmlp, W2T, bm2, x1, out, ROWS, D_MODEL, HID, 0, 1);
  } else {
    // ---------------- 32 MB fallback (round-5 proven) ----------------
    __bf16* hln  = (__bf16*)(w + 0 * MB);
    __bf16* vlin = (__bf16*)(w + 8 * MB);
    __bf16* WqT  = (__bf16*)(w + 16 * MB);
    __bf16* WkT  = (__bf16*)(w + 18 * MB);
    __bf16* WvT  = (__bf16*)(w + 20 * MB);
    __bf16* ctx  = (__bf16*)(w + 16 * MB);
    __bf16* WoT  = (__bf16*)(w + 8 * MB);
    __bf16* W1T  = (__bf16*)(w + 8 * MB);
    __bf16* W2T  = (__bf16*)(w + 16 * MB);
    __bf16* Vt   = (__bf16*)(w + 24 * MB);
    __bf16* hmlp = (__bf16*)(w + 24 * MB);
    __bf16* qlin = (__bf16*)d_out;
    __bf16* klin = (__bf16*)d_out + (size_t)ROWS * D_MODEL;
    float*  x1   = (float*)d_out;

    convT_kernel<<<gConvD, blk, 0, stream>>>(Wq, WqT, D_MODEL, D_MODEL);
    convT_kernel<<<gConvD, blk, 0, stream>>>(Wk, WkT, D_MODEL, D_MODEL);
    convT_kernel<<<gConvD, blk, 0, stream>>>(Wv, WvT, D_MODEL, D_MODEL);
    ln_kernel<<<ROWS, blk, 0, stream>>>(x, g1, b1, hln);
    dim3 gLin(ROWS / 64, D_MODEL / 128);
    gemm64x128<<<gLin, blk, 0, stream>>>(hln, WqT, bq, nullptr, qlin, ROWS, D_MODEL, D_MODEL, 0, 0);
    gemm64x128<<<gLin, blk, 0, stream>>>(hln, WkT, bk, nullptr, klin, ROWS, D_MODEL, D_MODEL, 0, 0);
    gemm64x128<<<gLin, blk, 0, stream>>>(hln, WvT, bv, nullptr, vlin, ROWS, D_MODEL, D_MODEL, 0, 0);
    rope_inplace<<<ROWS, blk, 0, stream>>>(qlin, klin, pos, D_MODEL);
    vtrans_kernel<<<gVt, blk, 0, stream>>>(vlin, D_MODEL, Vt, 0);
    attn_kernel<<<BATCH * NH * (SEQ / 64), blk, 0, stream>>>(qlin, klin, Vt, ctx, D_MODEL);
    convT_kernel<<<gConvD, blk, 0, stream>>>(Wo, WoT, D_MODEL, D_MODEL);
    gemm64x128<<<gLin, blk, 0, stream>>>(ctx, WoT, bo, x, x1, ROWS, D_MODEL, D_MODEL, 0, 1);
    ln_kernel<<<ROWS, blk, 0, stream>>>(x1, g2, b2, hln);
    convT_kernel<<<gConv1, blk, 0, stream>>>(W1, W1T, D_MODEL, HID);
    convT_kernel<<<gConv2, blk, 0, stream>>>(W2, W2T, HID, D_MODEL);
    const int CH = 1024;
    dim3 gC1(CH / 128, HID / 128);
    dim3 gC2(CH / 64, D_MODEL / 128);
    for (int c = 0; c < ROWS / CH; ++c) {
      const __bf16* a1 = hln + (size_t)c * CH * D_MODEL;
      gemm128<<<gC1, blk, 0, stream>>>(a1, W1T, bm1, nullptr, hmlp, CH, HID, D_MODEL, 1, 0);
      gemm64x128<<<gC2, blk, 0, stream>>>(hmlp, W2T, bm2, x1 + (size_t)c * CH * D_MODEL,
                                          out + (size_t)c * CH * D_MODEL, CH, D_MODEL, HID, 0, 1);
    }
  }
}

// Round 7
// 511.181 us; speedup vs baseline: 2.2205x; 1.2148x over previous
//
#include <hip/hip_runtime.h>

typedef __bf16 bf16x8 __attribute__((ext_vector_type(8)));
typedef __bf16 bf16x4 __attribute__((ext_vector_type(4)));
typedef float  f32x4  __attribute__((ext_vector_type(4)));

#define D_MODEL 1024
#define SEQ     2048
#define BATCH   2
#define NH      16
#define DH      64
#define HID     4096
#define ROWS    (BATCH*SEQ)

static __device__ __forceinline__ void gl_lds16(const __bf16* g, __bf16* l) {
  __builtin_amdgcn_global_load_lds(
      (const __attribute__((address_space(1))) unsigned int*)g,
      (__attribute__((address_space(3))) unsigned int*)l, 16, 0, 0);
}

// ------------------------------------------- LayerNorm: fp32 in, bf16 out
__global__ __launch_bounds__(256) void ln_kernel(
    const float* __restrict__ x, const float* __restrict__ g,
    const float* __restrict__ b, __bf16* __restrict__ out)
{
  int row = blockIdx.x;
  const float* xr = x + (size_t)row * D_MODEL;
  int i0 = threadIdx.x * 4;
  f32x4 xv = *(const f32x4*)(xr + i0);
  float s  = xv[0] + xv[1] + xv[2] + xv[3];
  float ss = xv[0]*xv[0] + xv[1]*xv[1] + xv[2]*xv[2] + xv[3]*xv[3];
#pragma unroll
  for (int off = 1; off < 64; off <<= 1) {
    s  += __shfl_xor(s,  off, 64);
    ss += __shfl_xor(ss, off, 64);
  }
  __shared__ float red[8];
  int wave = threadIdx.x >> 6;
  if ((threadIdx.x & 63) == 0) { red[wave] = s; red[4 + wave] = ss; }
  __syncthreads();
  s  = red[0] + red[1] + red[2] + red[3];
  ss = red[4] + red[5] + red[6] + red[7];
  float mu  = s * (1.0f / D_MODEL);
  float var = ss * (1.0f / D_MODEL) - mu * mu;
  float inv = rsqrtf(var + 1e-5f);
  f32x4 gv = *(const f32x4*)(g + i0);
  f32x4 bv = *(const f32x4*)(b + i0);
  bf16x4 ov;
#pragma unroll
  for (int j = 0; j < 4; ++j)
    ov[j] = (__bf16)((xv[j] - mu) * inv * gv[j] + bv[j]);
  *(bf16x4*)(out + (size_t)row * D_MODEL + i0) = ov;
}

// ---------------------- Weight convert+transpose: fp32 [K][N] -> bf16 [N][K]
__global__ __launch_bounds__(256) void convT_kernel(
    const float* __restrict__ W, __bf16* __restrict__ Wt, int K, int N)
{
  __shared__ float T[32][33];
  int n0 = blockIdx.x * 32, k0 = blockIdx.y * 32;
  int r  = threadIdx.x >> 3;
  int c4 = (threadIdx.x & 7) * 4;
  f32x4 v = *(const f32x4*)(W + (size_t)(k0 + r) * N + n0 + c4);
#pragma unroll
  for (int i = 0; i < 4; ++i) T[r][c4 + i] = v[i];
  __syncthreads();
  bf16x4 o;
#pragma unroll
  for (int i = 0; i < 4; ++i) o[i] = (__bf16)T[c4 + i][r];
  *(bf16x4*)(Wt + (size_t)(n0 + r) * K + k0 + c4) = o;
}

// ------------------------------- Bias concat: [bq | bk | bv] -> bqkv (fp32)
__global__ void biascat_kernel(const float* __restrict__ a,
                               const float* __restrict__ b,
                               const float* __restrict__ c,
                               float* __restrict__ o)
{
  int i = blockIdx.x * 256 + threadIdx.x;
  o[i] = i < 1024 ? a[i] : (i < 2048 ? b[i - 1024] : c[i - 2048]);
}

// ------------------------------------------------- m97-style 128x128 GEMM
__global__ __launch_bounds__(256) void gemm128(
    const __bf16* __restrict__ A, const __bf16* __restrict__ Bt,
    const float* __restrict__ bias, const float* __restrict__ resid,
    void* __restrict__ Cv, int M, int N, int K, int act, int c_fp32)
{
  __shared__ __bf16 As[128 * 32];
  __shared__ __bf16 Bs[128 * 32];
  int tid = threadIdx.x, lane = tid & 63, wv = tid >> 6;
  int quad = lane >> 4, l16 = lane & 15;
  int wr = wv >> 1, wc = wv & 1;
  int row0 = blockIdx.x * 128, col0 = blockIdx.y * 128;
  int srow = lane >> 2, skseg = (lane & 3) * 8;
  f32x4 acc[4][4] = {};

  for (int k0 = 0; k0 < K; k0 += 32) {
#pragma unroll
    for (int q = 0; q < 2; ++q) {
      int c = q * 4 + wv;
      int r = c * 16 + srow;
      gl_lds16(A  + (size_t)(row0 + r) * K + k0 + skseg, As + c * 512);
      gl_lds16(Bt + (size_t)(col0 + r) * K + k0 + skseg, Bs + c * 512);
    }
    __syncthreads();
    bf16x8 af[4], bf[4];
#pragma unroll
    for (int i = 0; i < 4; ++i) {
      af[i] = *(const bf16x8*)(As + (wr * 64 + i * 16 + l16) * 32 + quad * 8);
      bf[i] = *(const bf16x8*)(Bs + (wc * 64 + i * 16 + l16) * 32 + quad * 8);
    }
#pragma unroll
    for (int i = 0; i < 4; ++i)
#pragma unroll
      for (int j = 0; j < 4; ++j)
        acc[i][j] = __builtin_amdgcn_mfma_f32_16x16x32_bf16(af[i], bf[j], acc[i][j], 0, 0, 0);
    __syncthreads();
  }
#pragma unroll
  for (int i = 0; i < 4; ++i) {
    int grow = row0 + wr * 64 + i * 16 + quad * 4;
#pragma unroll
    for (int j = 0; j < 4; ++j) {
      int gcol = col0 + wc * 64 + j * 16 + l16;
      float bsv = bias[gcol];
#pragma unroll
      for (int r = 0; r < 4; ++r) {
        size_t off = (size_t)(grow + r) * N + gcol;
        float v = acc[i][j][r] + bsv;
        if (act) v = 0.5f * v * (1.0f + erff(v * 0.70710678118654752f));
        if (resid) v += resid[off];
        if (c_fp32) ((float*)Cv)[off] = v;
        else        ((__bf16*)Cv)[off] = (__bf16)v;
      }
    }
  }
}

// -------------------------------------- 64x128-tile GEMM (for N=1024 outputs)
__global__ __launch_bounds__(256) void gemm64x128(
    const __bf16* __restrict__ A, const __bf16* __restrict__ Bt,
    const float* __restrict__ bias, const float* __restrict__ resid,
    void* __restrict__ Cv, int M, int N, int K, int act, int c_fp32)
{
  __shared__ __bf16 As[64 * 32];
  __shared__ __bf16 Bs[128 * 32];
  int tid = threadIdx.x, lane = tid & 63, wv = tid >> 6;
  int quad = lane >> 4, l16 = lane & 15;
  int wr = wv >> 1, wc = wv & 1;
  int row0 = blockIdx.x * 64, col0 = blockIdx.y * 128;
  int srow = lane >> 2, skseg = (lane & 3) * 8;
  f32x4 acc[2][4] = {};

  for (int k0 = 0; k0 < K; k0 += 32) {
    {
      int r = wv * 16 + srow;
      gl_lds16(A + (size_t)(row0 + r) * K + k0 + skseg, As + wv * 512);
    }
#pragma unroll
    for (int q = 0; q < 2; ++q) {
      int c = q * 4 + wv;
      int r = c * 16 + srow;
      gl_lds16(Bt + (size_t)(col0 + r) * K + k0 + skseg, Bs + c * 512);
    }
    __syncthreads();
    bf16x8 af[2], bf[4];
#pragma unroll
    for (int i = 0; i < 2; ++i)
      af[i] = *(const bf16x8*)(As + (wr * 32 + i * 16 + l16) * 32 + quad * 8);
#pragma unroll
    for (int j = 0; j < 4; ++j)
      bf[j] = *(const bf16x8*)(Bs + (wc * 64 + j * 16 + l16) * 32 + quad * 8);
#pragma unroll
    for (int i = 0; i < 2; ++i)
#pragma unroll
      for (int j = 0; j < 4; ++j)
        acc[i][j] = __builtin_amdgcn_mfma_f32_16x16x32_bf16(af[i], bf[j], acc[i][j], 0, 0, 0);
    __syncthreads();
  }
#pragma unroll
  for (int i = 0; i < 2; ++i) {
    int grow = row0 + wr * 32 + i * 16 + quad * 4;
#pragma unroll
    for (int j = 0; j < 4; ++j) {
      int gcol = col0 + wc * 64 + j * 16 + l16;
      float bsv = bias[gcol];
#pragma unroll
      for (int r = 0; r < 4; ++r) {
        size_t off = (size_t)(grow + r) * N + gcol;
        float v = acc[i][j][r] + bsv;
        if (act) v = 0.5f * v * (1.0f + erff(v * 0.70710678118654752f));
        if (resid) v += resid[off];
        if (c_fp32) ((float*)Cv)[off] = v;
        else        ((__bf16*)Cv)[off] = (__bf16)v;
      }
    }
  }
}

// ------------------------- RoPE + repack qkv -> per-head Qh/Kh [bh][SEQ][64]
__global__ __launch_bounds__(256) void rope_repack(
    const __bf16* __restrict__ qkv, const int* __restrict__ pos,
    __bf16* __restrict__ Qh, __bf16* __restrict__ Kh)
{
  int row = blockIdx.x;
  int b = row >> 11, n = row & (SEQ - 1);
  float p = (float)pos[n];
  const __bf16* qr = qkv + (size_t)row * 3072;
#pragma unroll
  for (int t = 0; t < 2; ++t) {
    int i = threadIdx.x + t * 256;      // 0..511
    float fr  = expf(-9.210340371976184f * ((float)i * (1.0f / 512.0f)));
    float ang = p * fr;
    float sn, c;
    sincosf(ang, &sn, &c);
    float q1 = (float)qr[i],        q2 = (float)qr[512 + i];
    float k1 = (float)qr[1024 + i], k2 = (float)qr[1536 + i];
    int h1 = i >> 6, d1 = i & 63;
    int h2 = (i + 512) >> 6;
    size_t o1 = ((size_t)(b * NH + h1) * SEQ + n) * DH + d1;
    size_t o2 = ((size_t)(b * NH + h2) * SEQ + n) * DH + d1;
    Qh[o1] = (__bf16)(q1 * c - q2 * sn);
    Qh[o2] = (__bf16)(q1 * sn + q2 * c);
    Kh[o1] = (__bf16)(k1 * c - k2 * sn);
    Kh[o2] = (__bf16)(k1 * sn + k2 * c);
  }
}

// ----- V transpose. blocked=0: Vt[bh][64][SEQ]; blocked=1: Vt[bh][seg][64][128]
__global__ __launch_bounds__(256) void vtrans_kernel(
    const __bf16* __restrict__ Vsrc, int vstride, __bf16* __restrict__ Vt,
    int blocked)
{
  __shared__ __bf16 T[64][72];
  int bh = blockIdx.x;
  int kb = blockIdx.y * 64;
  int b = bh >> 4, h = bh & 15;
  int tid = threadIdx.x;
#pragma unroll
  for (int t = 0; t < 2; ++t) {
    int u = tid + t * 256;
    int r = u >> 3, seg = (u & 7) * 8;
    bf16x8 v = *(const bf16x8*)(Vsrc + (size_t)(b * SEQ + kb + r) * vstride + h * DH + seg);
    *(bf16x8*)(&T[r][seg]) = v;
  }
  __syncthreads();
#pragma unroll
  for (int t = 0; t < 2; ++t) {
    int u = tid + t * 256;
    int d = u >> 3, ks = (u & 7) * 8;
    bf16x8 o;
#pragma unroll
    for (int i = 0; i < 8; ++i) o[i] = T[ks + i][d];
    if (blocked) {
      int key = kb + ks;
      *(bf16x8*)(Vt + (((size_t)bh * (SEQ / 128) + (key >> 7)) * DH + d) * 128 + (key & 127)) = o;
    } else {
      *(bf16x8*)(Vt + ((size_t)bh * DH + d) * SEQ + kb + ks) = o;
    }
  }
}

// --- Flash attention, split-K=2, LDS-staged K/V tiles, XCD-swizzled blocks.
// blk encoding: split = blk>>10; r = blk&1023; bh = ((r&7)<<2)|((r>>3)&3);
// q64 = r>>5.  => blk%8 == bh>>2, so each XCD sees only 4 of 32 bh (L2 fit).
#define KS 136
__global__ __launch_bounds__(256) void attn_split(
    const __bf16* __restrict__ Qh, const __bf16* __restrict__ Kh,
    const __bf16* __restrict__ Vt, __bf16* __restrict__ pacc,
    float* __restrict__ pml)
{
  __shared__ __bf16 Ks[128 * 64];      // [key][d], linear
  __shared__ __bf16 Vs[64 * 128];      // [d][key], slot^d swizzled
  __shared__ __bf16 Pl[4][16 * KS];    // per-wave P [qrow][key]
  int tid = threadIdx.x, lane = tid & 63, wave = tid >> 6;
  int quad = lane >> 4, l16 = lane & 15;
  int blk = blockIdx.x;
  int split = blk >> 10;
  int rr = blk & 1023;
  int bh  = ((rr & 7) << 2) | ((rr >> 3) & 3);
  int q64 = rr >> 5;
  int q0 = q64 * 64 + wave * 16;
  const __bf16* qbase = Qh + (size_t)bh * SEQ * DH;
  const __bf16* kbase = Kh + (size_t)bh * SEQ * DH;
  const __bf16* vbase = Vt + (size_t)bh * SEQ * DH;   // blocked layout
  const __bf16* qp = qbase + (size_t)(q0 + l16) * DH + quad * 8;
  bf16x8 qf0 = *(const bf16x8*)(qp);
  bf16x8 qf1 = *(const bf16x8*)(qp + 32);
  float mrow[4] = {-1e30f, -1e30f, -1e30f, -1e30f};
  float lrow[4] = {0.f, 0.f, 0.f, 0.f};
  f32x4 acc[4] = {};
  __bf16* pw = &Pl[wave][0];
  // staging descriptors (constant over iterations)
  int s_kr = lane >> 3;                // 0..7
  int s_ks = (lane & 7) * 8;           // K seg (elements)
  int s_vd = lane >> 4;                // 0..3
  int s_vs = lane & 15;                // V slot

  int kb0 = split * (SEQ / 2);
  for (int it = 0; it < (SEQ / 2) / 128; ++it) {
    int kb = kb0 + it * 128;
    const __bf16* kt = kbase + (size_t)kb * DH;
    const __bf16* vt = vbase + (size_t)(kb >> 7) * (DH * 128);
    __syncthreads();                   // prev tile fully consumed
#pragma unroll
    for (int p = 0; p < 4; ++p) {
      int krow = p * 32 + wave * 8 + s_kr;
      gl_lds16(kt + krow * DH + s_ks, Ks + p * 2048 + wave * 512);
      int d = p * 16 + wave * 4 + s_vd;
      gl_lds16(vt + d * 128 + ((s_vs ^ (d & 15)) * 8), Vs + p * 2048 + wave * 512);
    }
    __syncthreads();                   // staging complete (vmcnt drained)
    // scores: key = l16*8 + j
    f32x4 s[8];
#pragma unroll
    for (int j = 0; j < 8; ++j) {
      const __bf16* kr = Ks + (l16 * 8 + j) * 64;
      bf16x8 kf0 = *(const bf16x8*)(kr + quad * 8);
      bf16x8 kf1 = *(const bf16x8*)(kr + 32 + quad * 8);
      f32x4 z = {};
      z = __builtin_amdgcn_mfma_f32_16x16x32_bf16(qf0, kf0, z, 0, 0, 0);
      z = __builtin_amdgcn_mfma_f32_16x16x32_bf16(qf1, kf1, z, 0, 0, 0);
#pragma unroll
      for (int r = 0; r < 4; ++r) s[j][r] = z[r] * 0.125f;   // 1/sqrt(64)
    }
#pragma unroll
    for (int r = 0; r < 4; ++r) {
      float mx = s[0][r];
#pragma unroll
      for (int j = 1; j < 8; ++j) mx = fmaxf(mx, s[j][r]);
#pragma unroll
      for (int off = 1; off < 16; off <<= 1) mx = fmaxf(mx, __shfl_xor(mx, off, 64));
      float mn = fmaxf(mrow[r], mx);
      float al = __expf(mrow[r] - mn);
      float p[8], rs = 0.f;
#pragma unroll
      for (int j = 0; j < 8; ++j) { p[j] = __expf(s[j][r] - mn); rs += p[j]; }
#pragma unroll
      for (int off = 1; off < 16; off <<= 1) rs += __shfl_xor(rs, off, 64);
      lrow[r] = lrow[r] * al + rs;
      mrow[r] = mn;
#pragma unroll
      for (int j = 0; j < 4; ++j) acc[j][r] *= al;
      bf16x8 pv;
#pragma unroll
      for (int j = 0; j < 8; ++j) pv[j] = (__bf16)p[j];
      *(bf16x8*)(pw + (quad * 4 + r) * KS + l16 * 8) = pv;
    }
    // PV: P per-wave (lgkmcnt-ordered), V fragments from swizzled LDS
#pragma unroll
    for (int kk = 0; kk < 4; ++kk) {
      bf16x8 pf = *(const bf16x8*)(pw + l16 * KS + kk * 32 + quad * 8);
#pragma unroll
      for (int j = 0; j < 4; ++j) {
        int d = j * 16 + l16;
        bf16x8 vf = *(const bf16x8*)(Vs + d * 128 + (((kk * 4 + quad) ^ (d & 15)) * 8));
        acc[j] = __builtin_amdgcn_mfma_f32_16x16x32_bf16(pf, vf, acc[j], 0, 0, 0);
      }
    }
  }
  // partial outputs: unnormalized acc (bf16) + m,l (fp32)
#pragma unroll
  for (int r = 0; r < 4; ++r) {
    int brow = wave * 16 + quad * 4 + r;
#pragma unroll
    for (int j = 0; j < 4; ++j)
      pacc[((size_t)blk * 64 + brow) * 64 + j * 16 + l16] = (__bf16)acc[j][r];
    if (l16 == 0) {
      pml[(size_t)blk * 128 + brow]      = mrow[r];
      pml[(size_t)blk * 128 + 64 + brow] = lrow[r];
    }
  }
}

// ------------------------------------------- combine 2 splits -> ctx (bf16)
__global__ __launch_bounds__(256) void attn_combine(
    const __bf16* __restrict__ pacc, const float* __restrict__ pml,
    __bf16* __restrict__ ctx)
{
  int bq = blockIdx.x;                // bh*32 + q64
  int q64 = bq & 31, bh = bq >> 5;
  int b = bh >> 4, h = bh & 15;
  int tid = threadIdx.x;
  int r = tid >> 2;                   // 0..63
  int c = (tid & 3) * 16;
  int blk0 = ((q64 * 4 + (bh & 3)) << 3) | (bh >> 2);   // split 0 (XCD swizzle)
  int blk1 = blk0 + 1024;                               // split 1
  float m0 = pml[(size_t)blk0 * 128 + r], l0 = pml[(size_t)blk0 * 128 + 64 + r];
  float m1 = pml[(size_t)blk1 * 128 + r], l1 = pml[(size_t)blk1 * 128 + 64 + r];
  float m = fmaxf(m0, m1);
  float w0 = __expf(m0 - m), w1 = __expf(m1 - m);
  float inv = 1.0f / (w0 * l0 + w1 * l1);
  size_t r0 = ((size_t)blk0 * 64 + r) * 64 + c;
  size_t r1 = ((size_t)blk1 * 64 + r) * 64 + c;
  size_t ob = ((size_t)(b * SEQ) + q64 * 64 + r) * D_MODEL + h * DH + c;
#pragma unroll
  for (int g = 0; g < 2; ++g) {
    bf16x8 a0 = *(const bf16x8*)(pacc + r0 + g * 8);
    bf16x8 a1 = *(const bf16x8*)(pacc + r1 + g * 8);
    bf16x8 o;
#pragma unroll
    for (int i = 0; i < 8; ++i)
      o[i] = (__bf16)((w0 * (float)a0[i] + w1 * (float)a1[i]) * inv);
    *(bf16x8*)(ctx + ob + g * 8) = o;
  }
}

// ------------ legacy kernels for the small-workspace fallback path ------------
__global__ __launch_bounds__(256) void rope_inplace(
    __bf16* __restrict__ ql, __bf16* __restrict__ kl,
    const int* __restrict__ pos, int stride)
{
  int row = blockIdx.x;
  int n = row & (SEQ - 1);
  float p = (float)pos[n];
  const size_t rbase = (size_t)row * stride;
#pragma unroll
  for (int t = 0; t < 2; ++t) {
    int i = threadIdx.x + t * 256;
    float fr  = expf(-9.210340371976184f * ((float)i * (1.0f / 512.0f)));
    float ang = p * fr;
    float sn, c;
    sincosf(ang, &sn, &c);
    float q1 = (float)ql[rbase + i], q2 = (float)ql[rbase + 512 + i];
    float k1 = (float)kl[rbase + i], k2 = (float)kl[rbase + 512 + i];
    ql[rbase + i]       = (__bf16)(q1 * c - q2 * sn);
    ql[rbase + 512 + i] = (__bf16)(q1 * sn + q2 * c);
    kl[rbase + i]       = (__bf16)(k1 * c - k2 * sn);
    kl[rbase + 512 + i] = (__bf16)(k1 * sn + k2 * c);
  }
}

__global__ __launch_bounds__(256) void attn_kernel(
    const __bf16* __restrict__ Q, const __bf16* __restrict__ K,
    const __bf16* __restrict__ Vt, __bf16* __restrict__ ctx, int qkstride)
{
  __shared__ __bf16 Pl[4][16 * KS];
  int tid = threadIdx.x, lane = tid & 63, wave = tid >> 6;
  int quad = lane >> 4, l16 = lane & 15;
  int blk = blockIdx.x;
  int q64 = blk & 31;
  int bh  = blk >> 5;
  int b = bh >> 4, h = bh & 15;
  int q0 = q64 * 64 + wave * 16;
  const __bf16* qbase = Q + (size_t)b * SEQ * qkstride + h * DH;
  const __bf16* kbase = K + (size_t)b * SEQ * qkstride + h * DH;
  const __bf16* vbase = Vt + (size_t)bh * DH * SEQ;
  const __bf16* qp = qbase + (size_t)(q0 + l16) * qkstride + quad * 8;
  bf16x8 qf0 = *(const bf16x8*)(qp);
  bf16x8 qf1 = *(const bf16x8*)(qp + 32);
  float mrow[4] = {-1e30f, -1e30f, -1e30f, -1e30f};
  float lrow[4] = {0.f, 0.f, 0.f, 0.f};
  f32x4 acc[4] = {};
  __bf16* pw = &Pl[wave][0];

  for (int kb = 0; kb < SEQ; kb += 128) {
    f32x4 s[8];
#pragma unroll
    for (int j = 0; j < 8; ++j) {
      const __bf16* kp = kbase + (size_t)(kb + l16 * 8 + j) * qkstride + quad * 8;
      bf16x8 kf0 = *(const bf16x8*)(kp);
      bf16x8 kf1 = *(const bf16x8*)(kp + 32);
      f32x4 z = {};
      z = __builtin_amdgcn_mfma_f32_16x16x32_bf16(qf0, kf0, z, 0, 0, 0);
      z = __builtin_amdgcn_mfma_f32_16x16x32_bf16(qf1, kf1, z, 0, 0, 0);
#pragma unroll
      for (int r = 0; r < 4; ++r) s[j][r] = z[r] * 0.125f;
    }
#pragma unroll
    for (int r = 0; r < 4; ++r) {
      float mx = s[0][r];
#pragma unroll
      for (int j = 1; j < 8; ++j) mx = fmaxf(mx, s[j][r]);
#pragma unroll
      for (int off = 1; off < 16; off <<= 1) mx = fmaxf(mx, __shfl_xor(mx, off, 64));
      float mn = fmaxf(mrow[r], mx);
      float al = __expf(mrow[r] - mn);
      float p[8], rs = 0.f;
#pragma unroll
      for (int j = 0; j < 8; ++j) { p[j] = __expf(s[j][r] - mn); rs += p[j]; }
#pragma unroll
      for (int off = 1; off < 16; off <<= 1) rs += __shfl_xor(rs, off, 64);
      lrow[r] = lrow[r] * al + rs;
      mrow[r] = mn;
#pragma unroll
      for (int j = 0; j < 4; ++j) acc[j][r] *= al;
      bf16x8 pv;
#pragma unroll
      for (int j = 0; j < 8; ++j) pv[j] = (__bf16)p[j];
      *(bf16x8*)(pw + (quad * 4 + r) * KS + l16 * 8) = pv;
    }
#pragma unroll
    for (int kk = 0; kk < 4; ++kk) {
      bf16x8 pf = *(const bf16x8*)(pw + l16 * KS + kk * 32 + quad * 8);
#pragma unroll
      for (int j = 0; j < 4; ++j) {
        bf16x8 vf = *(const bf16x8*)(vbase + (size_t)(j * 16 + l16) * SEQ + kb + kk * 32 + quad * 8);
        acc[j] = __builtin_amdgcn_mfma_f32_16x16x32_bf16(pf, vf, acc[j], 0, 0, 0);
      }
    }
  }
#pragma unroll
  for (int r = 0; r < 4; ++r) {
    int row = q0 + quad * 4 + r;
    float inv = 1.0f / lrow[r];
    size_t obase = ((size_t)(b * SEQ) + row) * D_MODEL + h * DH;
#pragma unroll
    for (int j = 0; j < 4; ++j)
      ctx[obase + j * 16 + l16] = (__bf16)(acc[j][r] * inv);
  }
}

// ------------------------------------------------------------------ launcher
extern "C" void kernel_launch(void* const* d_in, const int* in_sizes, int n_in,
                              void* d_out, int out_size, void* d_ws, size_t ws_size,
                              hipStream_t stream)
{
  const float* x   = (const float*)d_in[0];
  const int*   pos = (const int*)  d_in[1];
  const float* Wq  = (const float*)d_in[2];
  const float* bq  = (const float*)d_in[3];
  const float* Wk  = (const float*)d_in[4];
  const float* bk  = (const float*)d_in[5];
  const float* Wv  = (const float*)d_in[6];
  const float* bv  = (const float*)d_in[7];
  const float* Wo  = (const float*)d_in[8];
  const float* bo  = (const float*)d_in[9];
  const float* g1  = (const float*)d_in[10];
  const float* b1  = (const float*)d_in[11];
  const float* g2  = (const float*)d_in[12];
  const float* b2  = (const float*)d_in[13];
  const float* W1  = (const float*)d_in[14];
  const float* bm1 = (const float*)d_in[15];
  const float* W2  = (const float*)d_in[16];
  const float* bm2 = (const float*)d_in[17];
  float* out = (float*)d_out;

  const size_t MB = 1024 * 1024;
  char* w = (char*)d_ws;
  dim3 blk(256);
  dim3 gConvD(D_MODEL / 32, D_MODEL / 32);
  dim3 gConv1(HID / 32, D_MODEL / 32);
  dim3 gConv2(D_MODEL / 32, HID / 32);
  dim3 gVt(BATCH * NH, SEQ / 64);

  if (ws_size >= (size_t)96 * MB) {
    // ---------------- large path ----------------
    __bf16* hln   = (__bf16*)(w + 0 * MB);
    float*  x1    = (float*) (w + 8 * MB);
    __bf16* qkv   = (__bf16*)(w + 24 * MB);
    __bf16* pacc  = (__bf16*)(w + 24 * MB);
    float*  pml   = (float*) (w + 41 * MB);
    __bf16* hmlp  = (__bf16*)(w + 24 * MB);
    __bf16* Qh    = (__bf16*)(w + 48 * MB);
    __bf16* ctx   = (__bf16*)(w + 48 * MB);
    __bf16* Kh    = (__bf16*)(w + 56 * MB);
    __bf16* W2T   = (__bf16*)(w + 56 * MB);
    __bf16* Vt    = (__bf16*)(w + 64 * MB);
    __bf16* W1T   = (__bf16*)(w + 64 * MB);
    __bf16* WqkvT = (__bf16*)(w + 72 * MB);
    __bf16* WoT   = (__bf16*)(w + 78 * MB);
    float*  bqkv  = (float*) (w + 80 * MB);

    convT_kernel<<<gConvD, blk, 0, stream>>>(Wq, WqkvT,               D_MODEL, D_MODEL);
    convT_kernel<<<gConvD, blk, 0, stream>>>(Wk, WqkvT + 1024 * 1024, D_MODEL, D_MODEL);
    convT_kernel<<<gConvD, blk, 0, stream>>>(Wv, WqkvT + 2048 * 1024, D_MODEL, D_MODEL);
    convT_kernel<<<gConvD, blk, 0, stream>>>(Wo, WoT, D_MODEL, D_MODEL);
    biascat_kernel<<<12, blk, 0, stream>>>(bq, bk, bv, bqkv);
    ln_kernel<<<ROWS, blk, 0, stream>>>(x, g1, b1, hln);
    dim3 gQKV(ROWS / 128, 3072 / 128);
    gemm128<<<gQKV, blk, 0, stream>>>(hln, WqkvT, bqkv, nullptr, qkv, ROWS, 3072, D_MODEL, 0, 0);
    rope_repack<<<ROWS, blk, 0, stream>>>(qkv, pos, Qh, Kh);
    vtrans_kernel<<<gVt, blk, 0, stream>>>(qkv + 2048, 3072, Vt, 1);
    attn_split<<<BATCH * NH * (SEQ / 64) * 2, blk, 0, stream>>>(Qh, Kh, Vt, pacc, pml);
    attn_combine<<<BATCH * NH * (SEQ / 64), blk, 0, stream>>>(pacc, pml, ctx);
    convT_kernel<<<gConv1, blk, 0, stream>>>(W1, W1T, D_MODEL, HID);
    convT_kernel<<<gConv2, blk, 0, stream>>>(W2, W2T, HID, D_MODEL);
    dim3 gWo(ROWS / 64, D_MODEL / 128);
    gemm64x128<<<gWo, blk, 0, stream>>>(ctx, WoT, bo, x, x1, ROWS, D_MODEL, D_MODEL, 0, 1);
    ln_kernel<<<ROWS, blk, 0, stream>>>(x1, g2, b2, hln);
    dim3 gW1(ROWS / 128, HID / 128);
    gemm128<<<gW1, blk, 0, stream>>>(hln, W1T, bm1, nullptr, hmlp, ROWS, HID, D_MODEL, 1, 0);
    dim3 gW2(ROWS / 64, D_MODEL / 128);
    gemm64x128<<<gW2, blk, 0, stream>>>(hmlp, W2T, bm2, x1, out, ROWS, D_MODEL, HID, 0, 1);
  } else {
    // ---------------- 32 MB fallback (round-5 proven) ----------------
    __bf16* hln  = (__bf16*)(w + 0 * MB);
    __bf16* vlin = (__bf16*)(w + 8 * MB);
    __bf16* WqT  = (__bf16*)(w + 16 * MB);
    __bf16* WkT  = (__bf16*)(w + 18 * MB);
    __bf16* WvT  = (__bf16*)(w + 20 * MB);
    __bf16* ctx  = (__bf16*)(w + 16 * MB);
    __bf16* WoT  = (__bf16*)(w + 8 * MB);
    __bf16* W1T  = (__bf16*)(w + 8 * MB);
    __bf16* W2T  = (__bf16*)(w + 16 * MB);
    __bf16* Vt   = (__bf16*)(w + 24 * MB);
    __bf16* hmlp = (__bf16*)(w + 24 * MB);
    __bf16* qlin = (__bf16*)d_out;
    __bf16* klin = (__bf16*)d_out + (size_t)ROWS * D_MODEL;
    float*  x1   = (float*)d_out;

    convT_kernel<<<gConvD, blk, 0, stream>>>(Wq, WqT, D_MODEL, D_MODEL);
    convT_kernel<<<gConvD, blk, 0, stream>>>(Wk, WkT, D_MODEL, D_MODEL);
    convT_kernel<<<gConvD, blk, 0, stream>>>(Wv, WvT, D_MODEL, D_MODEL);
    ln_kernel<<<ROWS, blk, 0, stream>>>(x, g1, b1, hln);
    dim3 gLin(ROWS / 64, D_MODEL / 128);
    gemm64x128<<<gLin, blk, 0, stream>>>(hln, WqT, bq, nullptr, qlin, ROWS, D_MODEL, D_MODEL, 0, 0);
    gemm64x128<<<gLin, blk, 0, stream>>>(hln, WkT, bk, nullptr, klin, ROWS, D_MODEL, D_MODEL, 0, 0);
    gemm64x128<<<gLin, blk, 0, stream>>>(hln, WvT, bv, nullptr, vlin, ROWS, D_MODEL, D_MODEL, 0, 0);
    rope_inplace<<<ROWS, blk, 0, stream>>>(qlin, klin, pos, D_MODEL);
    vtrans_kernel<<<gVt, blk, 0, stream>>>(vlin, D_MODEL, Vt, 0);
    attn_kernel<<<BATCH * NH * (SEQ / 64), blk, 0, stream>>>(qlin, klin, Vt, ctx, D_MODEL);
    convT_kernel<<<gConvD, blk, 0, stream>>>(Wo, WoT, D_MODEL, D_MODEL);
    gemm64x128<<<gLin, blk, 0, stream>>>(ctx, WoT, bo, x, x1, ROWS, D_MODEL, D_MODEL, 0, 1);
    ln_kernel<<<ROWS, blk, 0, stream>>>(x1, g2, b2, hln);
    convT_kernel<<<gConv1, blk, 0, stream>>>(W1, W1T, D_MODEL, HID);
    convT_kernel<<<gConv2, blk, 0, stream>>>(W2, W2T, HID, D_MODEL);
    const int CH = 1024;
    dim3 gC1(CH / 128, HID / 128);
    dim3 gC2(CH / 64, D_MODEL / 128);
    for (int c = 0; c < ROWS / CH; ++c) {
      const __bf16* a1 = hln + (size_t)c * CH * D_MODEL;
      gemm128<<<gC1, blk, 0, stream>>>(a1, W1T, bm1, nullptr, hmlp, CH, HID, D_MODEL, 1, 0);
      gemm64x128<<<gC2, blk, 0, stream>>>(hmlp, W2T, bm2, x1 + (size_t)c * CH * D_MODEL,
                                          out + (size_t)c * CH * D_MODEL, CH, D_MODEL, HID, 0, 1);
    }
  }
}

// Round 8
// 488.334 us; speedup vs baseline: 2.3244x; 1.0468x over previous
//
#include <hip/hip_runtime.h>

typedef __bf16 bf16x8 __attribute__((ext_vector_type(8)));
typedef __bf16 bf16x4 __attribute__((ext_vector_type(4)));
typedef float  f32x4  __attribute__((ext_vector_type(4)));

#define D_MODEL 1024
#define SEQ     2048
#define BATCH   2
#define NH      16
#define DH      64
#define HID     4096
#define ROWS    (BATCH*SEQ)

static __device__ __forceinline__ void gl_lds16(const __bf16* g, __bf16* l) {
  __builtin_amdgcn_global_load_lds(
      (const __attribute__((address_space(1))) unsigned int*)g,
      (__attribute__((address_space(3))) unsigned int*)l, 16, 0, 0);
}

// ------------------------------------------- LayerNorm: fp32 in, bf16 out
__global__ __launch_bounds__(256) void ln_kernel(
    const float* __restrict__ x, const float* __restrict__ g,
    const float* __restrict__ b, __bf16* __restrict__ out)
{
  int row = blockIdx.x;
  const float* xr = x + (size_t)row * D_MODEL;
  int i0 = threadIdx.x * 4;
  f32x4 xv = *(const f32x4*)(xr + i0);
  float s  = xv[0] + xv[1] + xv[2] + xv[3];
  float ss = xv[0]*xv[0] + xv[1]*xv[1] + xv[2]*xv[2] + xv[3]*xv[3];
#pragma unroll
  for (int off = 1; off < 64; off <<= 1) {
    s  += __shfl_xor(s,  off, 64);
    ss += __shfl_xor(ss, off, 64);
  }
  __shared__ float red[8];
  int wave = threadIdx.x >> 6;
  if ((threadIdx.x & 63) == 0) { red[wave] = s; red[4 + wave] = ss; }
  __syncthreads();
  s  = red[0] + red[1] + red[2] + red[3];
  ss = red[4] + red[5] + red[6] + red[7];
  float mu  = s * (1.0f / D_MODEL);
  float var = ss * (1.0f / D_MODEL) - mu * mu;
  float inv = rsqrtf(var + 1e-5f);
  f32x4 gv = *(const f32x4*)(g + i0);
  f32x4 bv = *(const f32x4*)(b + i0);
  bf16x4 ov;
#pragma unroll
  for (int j = 0; j < 4; ++j)
    ov[j] = (__bf16)((xv[j] - mu) * inv * gv[j] + bv[j]);
  *(bf16x4*)(out + (size_t)row * D_MODEL + i0) = ov;
}

// ---------------------- Weight convert+transpose: fp32 [K][N] -> bf16 [N][K]
__global__ __launch_bounds__(256) void convT_kernel(
    const float* __restrict__ W, __bf16* __restrict__ Wt, int K, int N)
{
  __shared__ float T[32][33];
  int n0 = blockIdx.x * 32, k0 = blockIdx.y * 32;
  int r  = threadIdx.x >> 3;
  int c4 = (threadIdx.x & 7) * 4;
  f32x4 v = *(const f32x4*)(W + (size_t)(k0 + r) * N + n0 + c4);
#pragma unroll
  for (int i = 0; i < 4; ++i) T[r][c4 + i] = v[i];
  __syncthreads();
  bf16x4 o;
#pragma unroll
  for (int i = 0; i < 4; ++i) o[i] = (__bf16)T[c4 + i][r];
  *(bf16x4*)(Wt + (size_t)(n0 + r) * K + k0 + c4) = o;
}

// ------------------------------- Bias concat: [bq | bk | bv] -> bqkv (fp32)
__global__ void biascat_kernel(const float* __restrict__ a,
                               const float* __restrict__ b,
                               const float* __restrict__ c,
                               float* __restrict__ o)
{
  int i = blockIdx.x * 256 + threadIdx.x;
  o[i] = i < 1024 ? a[i] : (i < 2048 ? b[i - 1024] : c[i - 2048]);
}

// ------------------- m97-style 128x128 GEMM, XCD column-panel swizzle.
// 1D grid of (M/128)*(N/128) blocks; xcd = blk&7 owns cols [xcd*N/8, ...).
__global__ __launch_bounds__(256) void gemm128(
    const __bf16* __restrict__ A, const __bf16* __restrict__ Bt,
    const float* __restrict__ bias, const float* __restrict__ resid,
    void* __restrict__ Cv, int M, int N, int K, int act, int c_fp32)
{
  __shared__ __bf16 As[128 * 32];
  __shared__ __bf16 Bs[128 * 32];
  int tid = threadIdx.x, lane = tid & 63, wv = tid >> 6;
  int quad = lane >> 4, l16 = lane & 15;
  int wr = wv >> 1, wc = wv & 1;
  int gx = M >> 7, gy = N >> 7;
  int blk = blockIdx.x;
  int xcd = blk & 7, t = blk >> 3;
  int row0 = (t % gx) * 128;
  int col0 = (xcd * (gy >> 3) + t / gx) * 128;
  int srow = lane >> 2, skseg = (lane & 3) * 8;
  f32x4 acc[4][4] = {};

  for (int k0 = 0; k0 < K; k0 += 32) {
#pragma unroll
    for (int q = 0; q < 2; ++q) {
      int c = q * 4 + wv;
      int r = c * 16 + srow;
      gl_lds16(A  + (size_t)(row0 + r) * K + k0 + skseg, As + c * 512);
      gl_lds16(Bt + (size_t)(col0 + r) * K + k0 + skseg, Bs + c * 512);
    }
    __syncthreads();
    bf16x8 af[4], bf[4];
#pragma unroll
    for (int i = 0; i < 4; ++i) {
      af[i] = *(const bf16x8*)(As + (wr * 64 + i * 16 + l16) * 32 + quad * 8);
      bf[i] = *(const bf16x8*)(Bs + (wc * 64 + i * 16 + l16) * 32 + quad * 8);
    }
#pragma unroll
    for (int i = 0; i < 4; ++i)
#pragma unroll
      for (int j = 0; j < 4; ++j)
        acc[i][j] = __builtin_amdgcn_mfma_f32_16x16x32_bf16(af[i], bf[j], acc[i][j], 0, 0, 0);
    __syncthreads();
  }
#pragma unroll
  for (int i = 0; i < 4; ++i) {
    int grow = row0 + wr * 64 + i * 16 + quad * 4;
#pragma unroll
    for (int j = 0; j < 4; ++j) {
      int gcol = col0 + wc * 64 + j * 16 + l16;
      float bsv = bias[gcol];
#pragma unroll
      for (int r = 0; r < 4; ++r) {
        size_t off = (size_t)(grow + r) * N + gcol;
        float v = acc[i][j][r] + bsv;
        if (act) v = 0.5f * v * (1.0f + erff(v * 0.70710678118654752f));
        if (resid) v += resid[off];
        if (c_fp32) ((float*)Cv)[off] = v;
        else        ((__bf16*)Cv)[off] = (__bf16)v;
      }
    }
  }
}

// ---------------- 64x128-tile GEMM (N=1024 outputs), XCD column swizzle
__global__ __launch_bounds__(256) void gemm64x128(
    const __bf16* __restrict__ A, const __bf16* __restrict__ Bt,
    const float* __restrict__ bias, const float* __restrict__ resid,
    void* __restrict__ Cv, int M, int N, int K, int act, int c_fp32)
{
  __shared__ __bf16 As[64 * 32];
  __shared__ __bf16 Bs[128 * 32];
  int tid = threadIdx.x, lane = tid & 63, wv = tid >> 6;
  int quad = lane >> 4, l16 = lane & 15;
  int wr = wv >> 1, wc = wv & 1;
  int gx = M >> 6, gy = N >> 7;
  int blk = blockIdx.x;
  int xcd = blk & 7, t = blk >> 3;
  int row0 = (t % gx) * 64;
  int col0 = (xcd * (gy >> 3) + t / gx) * 128;
  int srow = lane >> 2, skseg = (lane & 3) * 8;
  f32x4 acc[2][4] = {};

  for (int k0 = 0; k0 < K; k0 += 32) {
    {
      int r = wv * 16 + srow;
      gl_lds16(A + (size_t)(row0 + r) * K + k0 + skseg, As + wv * 512);
    }
#pragma unroll
    for (int q = 0; q < 2; ++q) {
      int c = q * 4 + wv;
      int r = c * 16 + srow;
      gl_lds16(Bt + (size_t)(col0 + r) * K + k0 + skseg, Bs + c * 512);
    }
    __syncthreads();
    bf16x8 af[2], bf[4];
#pragma unroll
    for (int i = 0; i < 2; ++i)
      af[i] = *(const bf16x8*)(As + (wr * 32 + i * 16 + l16) * 32 + quad * 8);
#pragma unroll
    for (int j = 0; j < 4; ++j)
      bf[j] = *(const bf16x8*)(Bs + (wc * 64 + j * 16 + l16) * 32 + quad * 8);
#pragma unroll
    for (int i = 0; i < 2; ++i)
#pragma unroll
      for (int j = 0; j < 4; ++j)
        acc[i][j] = __builtin_amdgcn_mfma_f32_16x16x32_bf16(af[i], bf[j], acc[i][j], 0, 0, 0);
    __syncthreads();
  }
#pragma unroll
  for (int i = 0; i < 2; ++i) {
    int grow = row0 + wr * 32 + i * 16 + quad * 4;
#pragma unroll
    for (int j = 0; j < 4; ++j) {
      int gcol = col0 + wc * 64 + j * 16 + l16;
      float bsv = bias[gcol];
#pragma unroll
      for (int r = 0; r < 4; ++r) {
        size_t off = (size_t)(grow + r) * N + gcol;
        float v = acc[i][j][r] + bsv;
        if (act) v = 0.5f * v * (1.0f + erff(v * 0.70710678118654752f));
        if (resid) v += resid[off];
        if (c_fp32) ((float*)Cv)[off] = v;
        else        ((__bf16*)Cv)[off] = (__bf16)v;
      }
    }
  }
}

// ------------------------- RoPE + repack qkv -> per-head Qh/Kh [bh][SEQ][64]
__global__ __launch_bounds__(256) void rope_repack(
    const __bf16* __restrict__ qkv, const int* __restrict__ pos,
    __bf16* __restrict__ Qh, __bf16* __restrict__ Kh)
{
  int row = blockIdx.x;
  int b = row >> 11, n = row & (SEQ - 1);
  float p = (float)pos[n];
  const __bf16* qr = qkv + (size_t)row * 3072;
#pragma unroll
  for (int t = 0; t < 2; ++t) {
    int i = threadIdx.x + t * 256;      // 0..511
    float fr  = expf(-9.210340371976184f * ((float)i * (1.0f / 512.0f)));
    float ang = p * fr;
    float sn, c;
    sincosf(ang, &sn, &c);
    float q1 = (float)qr[i],        q2 = (float)qr[512 + i];
    float k1 = (float)qr[1024 + i], k2 = (float)qr[1536 + i];
    int h1 = i >> 6, d1 = i & 63;
    int h2 = (i + 512) >> 6;
    size_t o1 = ((size_t)(b * NH + h1) * SEQ + n) * DH + d1;
    size_t o2 = ((size_t)(b * NH + h2) * SEQ + n) * DH + d1;
    Qh[o1] = (__bf16)(q1 * c - q2 * sn);
    Qh[o2] = (__bf16)(q1 * sn + q2 * c);
    Kh[o1] = (__bf16)(k1 * c - k2 * sn);
    Kh[o2] = (__bf16)(k1 * sn + k2 * c);
  }
}

// ----- V transpose. blocked=0: Vt[bh][64][SEQ]; blocked=1: Vt[bh][seg][64][128]
__global__ __launch_bounds__(256) void vtrans_kernel(
    const __bf16* __restrict__ Vsrc, int vstride, __bf16* __restrict__ Vt,
    int blocked)
{
  __shared__ __bf16 T[64][72];
  int bh = blockIdx.x;
  int kb = blockIdx.y * 64;
  int b = bh >> 4, h = bh & 15;
  int tid = threadIdx.x;
#pragma unroll
  for (int t = 0; t < 2; ++t) {
    int u = tid + t * 256;
    int r = u >> 3, seg = (u & 7) * 8;
    bf16x8 v = *(const bf16x8*)(Vsrc + (size_t)(b * SEQ + kb + r) * vstride + h * DH + seg);
    *(bf16x8*)(&T[r][seg]) = v;
  }
  __syncthreads();
#pragma unroll
  for (int t = 0; t < 2; ++t) {
    int u = tid + t * 256;
    int d = u >> 3, ks = (u & 7) * 8;
    bf16x8 o;
#pragma unroll
    for (int i = 0; i < 8; ++i) o[i] = T[ks + i][d];
    if (blocked) {
      int key = kb + ks;
      *(bf16x8*)(Vt + (((size_t)bh * (SEQ / 128) + (key >> 7)) * DH + d) * 128 + (key & 127)) = o;
    } else {
      *(bf16x8*)(Vt + ((size_t)bh * DH + d) * SEQ + kb + ks) = o;
    }
  }
}

// --- Flash attention, split-K=2, LDS K/V tiles (XOR-swizzled), XCD swizzle.
#define KS 136
__global__ __launch_bounds__(256) void attn_split(
    const __bf16* __restrict__ Qh, const __bf16* __restrict__ Kh,
    const __bf16* __restrict__ Vt, __bf16* __restrict__ pacc,
    float* __restrict__ pml)
{
  __shared__ __bf16 Ks[128 * 64];      // [key][slot], slot = seg ^ ((key>>3)&7)
  __shared__ __bf16 Vs[64 * 128];      // [d][slot], slot = seg ^ (d&15)
  __shared__ __bf16 Pl[4][16 * KS];    // per-wave P [qrow][key]
  int tid = threadIdx.x, lane = tid & 63, wave = tid >> 6;
  int quad = lane >> 4, l16 = lane & 15;
  int blk = blockIdx.x;
  int split = blk >> 10;
  int rr = blk & 1023;
  int bh  = ((rr & 7) << 2) | ((rr >> 3) & 3);
  int q64 = rr >> 5;
  int q0 = q64 * 64 + wave * 16;
  const __bf16* qbase = Qh + (size_t)bh * SEQ * DH;
  const __bf16* kbase = Kh + (size_t)bh * SEQ * DH;
  const __bf16* vbase = Vt + (size_t)bh * SEQ * DH;   // blocked layout
  const __bf16* qp = qbase + (size_t)(q0 + l16) * DH + quad * 8;
  bf16x8 qf0 = *(const bf16x8*)(qp);
  bf16x8 qf1 = *(const bf16x8*)(qp + 32);
  float mrow[4] = {-1e30f, -1e30f, -1e30f, -1e30f};
  float lrow[4] = {0.f, 0.f, 0.f, 0.f};
  f32x4 acc[4] = {};
  __bf16* pw = &Pl[wave][0];
  int s_kr = lane >> 3;                // K row within issue: 0..7
  int s_k8 = lane & 7;                 // K slot: 0..7
  int s_vd = lane >> 4;                // V d within issue: 0..3
  int s_vs = lane & 15;                // V slot: 0..15
  int sw8  = l16 & 7;                  // K read swizzle

  int kb0 = split * (SEQ / 2);
  for (int it = 0; it < (SEQ / 2) / 128; ++it) {
    int kb = kb0 + it * 128;
    const __bf16* kt = kbase + (size_t)kb * DH;
    const __bf16* vt = vbase + (size_t)(kb >> 7) * (DH * 128);
    __syncthreads();                   // prev tile fully consumed
#pragma unroll
    for (int p = 0; p < 4; ++p) {
      int key0 = p * 32 + wave * 8;
      int swz  = (key0 >> 3) & 7;
      gl_lds16(kt + (key0 + s_kr) * DH + ((s_k8 ^ swz) * 8), Ks + p * 2048 + wave * 512);
      int d = p * 16 + wave * 4 + s_vd;
      gl_lds16(vt + d * 128 + ((s_vs ^ (d & 15)) * 8), Vs + p * 2048 + wave * 512);
    }
    __syncthreads();                   // staging complete
    // scores: key = l16*8 + j; K slots de-swizzled by quad^sw8
    f32x4 s[8];
#pragma unroll
    for (int j = 0; j < 8; ++j) {
      const __bf16* kr = Ks + (l16 * 8 + j) * 64;
      bf16x8 kf0 = *(const bf16x8*)(kr + (quad ^ sw8) * 8);
      bf16x8 kf1 = *(const bf16x8*)(kr + ((quad ^ sw8) ^ 4) * 8);
      f32x4 z = {};
      z = __builtin_amdgcn_mfma_f32_16x16x32_bf16(qf0, kf0, z, 0, 0, 0);
      z = __builtin_amdgcn_mfma_f32_16x16x32_bf16(qf1, kf1, z, 0, 0, 0);
#pragma unroll
      for (int r = 0; r < 4; ++r) s[j][r] = z[r] * 0.125f;   // 1/sqrt(64)
    }
#pragma unroll
    for (int r = 0; r < 4; ++r) {
      float mx = s[0][r];
#pragma unroll
      for (int j = 1; j < 8; ++j) mx = fmaxf(mx, s[j][r]);
#pragma unroll
      for (int off = 1; off < 16; off <<= 1) mx = fmaxf(mx, __shfl_xor(mx, off, 64));
      float mn = fmaxf(mrow[r], mx);
      float al = __expf(mrow[r] - mn);
      float p[8], rs = 0.f;
#pragma unroll
      for (int j = 0; j < 8; ++j) { p[j] = __expf(s[j][r] - mn); rs += p[j]; }
#pragma unroll
      for (int off = 1; off < 16; off <<= 1) rs += __shfl_xor(rs, off, 64);
      lrow[r] = lrow[r] * al + rs;
      mrow[r] = mn;
#pragma unroll
      for (int j = 0; j < 4; ++j) acc[j][r] *= al;
      bf16x8 pv;
#pragma unroll
      for (int j = 0; j < 8; ++j) pv[j] = (__bf16)p[j];
      *(bf16x8*)(pw + (quad * 4 + r) * KS + l16 * 8) = pv;
    }
    // PV: P per-wave (lgkmcnt-ordered), V fragments from swizzled LDS
#pragma unroll
    for (int kk = 0; kk < 4; ++kk) {
      bf16x8 pf = *(const bf16x8*)(pw + l16 * KS + kk * 32 + quad * 8);
#pragma unroll
      for (int j = 0; j < 4; ++j) {
        int d = j * 16 + l16;
        bf16x8 vf = *(const bf16x8*)(Vs + d * 128 + (((kk * 4 + quad) ^ (d & 15)) * 8));
        acc[j] = __builtin_amdgcn_mfma_f32_16x16x32_bf16(pf, vf, acc[j], 0, 0, 0);
      }
    }
  }
  // partial outputs: unnormalized acc (bf16) + m,l (fp32)
#pragma unroll
  for (int r = 0; r < 4; ++r) {
    int brow = wave * 16 + quad * 4 + r;
#pragma unroll
    for (int j = 0; j < 4; ++j)
      pacc[((size_t)blk * 64 + brow) * 64 + j * 16 + l16] = (__bf16)acc[j][r];
    if (l16 == 0) {
      pml[(size_t)blk * 128 + brow]      = mrow[r];
      pml[(size_t)blk * 128 + 64 + brow] = lrow[r];
    }
  }
}

// ------------------------------------------- combine 2 splits -> ctx (bf16)
__global__ __launch_bounds__(256) void attn_combine(
    const __bf16* __restrict__ pacc, const float* __restrict__ pml,
    __bf16* __restrict__ ctx)
{
  int bq = blockIdx.x;                // bh*32 + q64
  int q64 = bq & 31, bh = bq >> 5;
  int b = bh >> 4, h = bh & 15;
  int tid = threadIdx.x;
  int r = tid >> 2;                   // 0..63
  int c = (tid & 3) * 16;
  int blk0 = ((q64 * 4 + (bh & 3)) << 3) | (bh >> 2);   // split 0 (XCD swizzle)
  int blk1 = blk0 + 1024;                               // split 1
  float m0 = pml[(size_t)blk0 * 128 + r], l0 = pml[(size_t)blk0 * 128 + 64 + r];
  float m1 = pml[(size_t)blk1 * 128 + r], l1 = pml[(size_t)blk1 * 128 + 64 + r];
  float m = fmaxf(m0, m1);
  float w0 = __expf(m0 - m), w1 = __expf(m1 - m);
  float inv = 1.0f / (w0 * l0 + w1 * l1);
  size_t r0 = ((size_t)blk0 * 64 + r) * 64 + c;
  size_t r1 = ((size_t)blk1 * 64 + r) * 64 + c;
  size_t ob = ((size_t)(b * SEQ) + q64 * 64 + r) * D_MODEL + h * DH + c;
#pragma unroll
  for (int g = 0; g < 2; ++g) {
    bf16x8 a0 = *(const bf16x8*)(pacc + r0 + g * 8);
    bf16x8 a1 = *(const bf16x8*)(pacc + r1 + g * 8);
    bf16x8 o;
#pragma unroll
    for (int i = 0; i < 8; ++i)
      o[i] = (__bf16)((w0 * (float)a0[i] + w1 * (float)a1[i]) * inv);
    *(bf16x8*)(ctx + ob + g * 8) = o;
  }
}

// ------------ legacy kernels for the small-workspace fallback path ------------
__global__ __launch_bounds__(256) void rope_inplace(
    __bf16* __restrict__ ql, __bf16* __restrict__ kl,
    const int* __restrict__ pos, int stride)
{
  int row = blockIdx.x;
  int n = row & (SEQ - 1);
  float p = (float)pos[n];
  const size_t rbase = (size_t)row * stride;
#pragma unroll
  for (int t = 0; t < 2; ++t) {
    int i = threadIdx.x + t * 256;
    float fr  = expf(-9.210340371976184f * ((float)i * (1.0f / 512.0f)));
    float ang = p * fr;
    float sn, c;
    sincosf(ang, &sn, &c);
    float q1 = (float)ql[rbase + i], q2 = (float)ql[rbase + 512 + i];
    float k1 = (float)kl[rbase + i], k2 = (float)kl[rbase + 512 + i];
    ql[rbase + i]       = (__bf16)(q1 * c - q2 * sn);
    ql[rbase + 512 + i] = (__bf16)(q1 * sn + q2 * c);
    kl[rbase + i]       = (__bf16)(k1 * c - k2 * sn);
    kl[rbase + 512 + i] = (__bf16)(k1 * sn + k2 * c);
  }
}

__global__ __launch_bounds__(256) void attn_kernel(
    const __bf16* __restrict__ Q, const __bf16* __restrict__ K,
    const __bf16* __restrict__ Vt, __bf16* __restrict__ ctx, int qkstride)
{
  __shared__ __bf16 Pl[4][16 * KS];
  int tid = threadIdx.x, lane = tid & 63, wave = tid >> 6;
  int quad = lane >> 4, l16 = lane & 15;
  int blk = blockIdx.x;
  int q64 = blk & 31;
  int bh  = blk >> 5;
  int b = bh >> 4, h = bh & 15;
  int q0 = q64 * 64 + wave * 16;
  const __bf16* qbase = Q + (size_t)b * SEQ * qkstride + h * DH;
  const __bf16* kbase = K + (size_t)b * SEQ * qkstride + h * DH;
  const __bf16* vbase = Vt + (size_t)bh * DH * SEQ;
  const __bf16* qp = qbase + (size_t)(q0 + l16) * qkstride + quad * 8;
  bf16x8 qf0 = *(const bf16x8*)(qp);
  bf16x8 qf1 = *(const bf16x8*)(qp + 32);
  float mrow[4] = {-1e30f, -1e30f, -1e30f, -1e30f};
  float lrow[4] = {0.f, 0.f, 0.f, 0.f};
  f32x4 acc[4] = {};
  __bf16* pw = &Pl[wave][0];

  for (int kb = 0; kb < SEQ; kb += 128) {
    f32x4 s[8];
#pragma unroll
    for (int j = 0; j < 8; ++j) {
      const __bf16* kp = kbase + (size_t)(kb + l16 * 8 + j) * qkstride + quad * 8;
      bf16x8 kf0 = *(const bf16x8*)(kp);
      bf16x8 kf1 = *(const bf16x8*)(kp + 32);
      f32x4 z = {};
      z = __builtin_amdgcn_mfma_f32_16x16x32_bf16(qf0, kf0, z, 0, 0, 0);
      z = __builtin_amdgcn_mfma_f32_16x16x32_bf16(qf1, kf1, z, 0, 0, 0);
#pragma unroll
      for (int r = 0; r < 4; ++r) s[j][r] = z[r] * 0.125f;
    }
#pragma unroll
    for (int r = 0; r < 4; ++r) {
      float mx = s[0][r];
#pragma unroll
      for (int j = 1; j < 8; ++j) mx = fmaxf(mx, s[j][r]);
#pragma unroll
      for (int off = 1; off < 16; off <<= 1) mx = fmaxf(mx, __shfl_xor(mx, off, 64));
      float mn = fmaxf(mrow[r], mx);
      float al = __expf(mrow[r] - mn);
      float p[8], rs = 0.f;
#pragma unroll
      for (int j = 0; j < 8; ++j) { p[j] = __expf(s[j][r] - mn); rs += p[j]; }
#pragma unroll
      for (int off = 1; off < 16; off <<= 1) rs += __shfl_xor(rs, off, 64);
      lrow[r] = lrow[r] * al + rs;
      mrow[r] = mn;
#pragma unroll
      for (int j = 0; j < 4; ++j) acc[j][r] *= al;
      bf16x8 pv;
#pragma unroll
      for (int j = 0; j < 8; ++j) pv[j] = (__bf16)p[j];
      *(bf16x8*)(pw + (quad * 4 + r) * KS + l16 * 8) = pv;
    }
#pragma unroll
    for (int kk = 0; kk < 4; ++kk) {
      bf16x8 pf = *(const bf16x8*)(pw + l16 * KS + kk * 32 + quad * 8);
#pragma unroll
      for (int j = 0; j < 4; ++j) {
        bf16x8 vf = *(const bf16x8*)(vbase + (size_t)(j * 16 + l16) * SEQ + kb + kk * 32 + quad * 8);
        acc[j] = __builtin_amdgcn_mfma_f32_16x16x32_bf16(pf, vf, acc[j], 0, 0, 0);
      }
    }
  }
#pragma unroll
  for (int r = 0; r < 4; ++r) {
    int row = q0 + quad * 4 + r;
    float inv = 1.0f / lrow[r];
    size_t obase = ((size_t)(b * SEQ) + row) * D_MODEL + h * DH;
#pragma unroll
    for (int j = 0; j < 4; ++j)
      ctx[obase + j * 16 + l16] = (__bf16)(acc[j][r] * inv);
  }
}

// ------------------------------------------------------------------ launcher
extern "C" void kernel_launch(void* const* d_in, const int* in_sizes, int n_in,
                              void* d_out, int out_size, void* d_ws, size_t ws_size,
                              hipStream_t stream)
{
  const float* x   = (const float*)d_in[0];
  const int*   pos = (const int*)  d_in[1];
  const float* Wq  = (const float*)d_in[2];
  const float* bq  = (const float*)d_in[3];
  const float* Wk  = (const float*)d_in[4];
  const float* bk  = (const float*)d_in[5];
  const float* Wv  = (const float*)d_in[6];
  const float* bv  = (const float*)d_in[7];
  const float* Wo  = (const float*)d_in[8];
  const float* bo  = (const float*)d_in[9];
  const float* g1  = (const float*)d_in[10];
  const float* b1  = (const float*)d_in[11];
  const float* g2  = (const float*)d_in[12];
  const float* b2  = (const float*)d_in[13];
  const float* W1  = (const float*)d_in[14];
  const float* bm1 = (const float*)d_in[15];
  const float* W2  = (const float*)d_in[16];
  const float* bm2 = (const float*)d_in[17];
  float* out = (float*)d_out;

  const size_t MB = 1024 * 1024;
  char* w = (char*)d_ws;
  dim3 blk(256);
  dim3 gConvD(D_MODEL / 32, D_MODEL / 32);
  dim3 gConv1(HID / 32, D_MODEL / 32);
  dim3 gConv2(D_MODEL / 32, HID / 32);
  dim3 gVt(BATCH * NH, SEQ / 64);

  if (ws_size >= (size_t)96 * MB) {
    // ---------------- large path ----------------
    __bf16* hln   = (__bf16*)(w + 0 * MB);
    float*  x1    = (float*) (w + 8 * MB);
    __bf16* qkv   = (__bf16*)(w + 24 * MB);
    __bf16* pacc  = (__bf16*)(w + 24 * MB);
    float*  pml   = (float*) (w + 41 * MB);
    __bf16* hmlp  = (__bf16*)(w + 24 * MB);
    __bf16* Qh    = (__bf16*)(w + 48 * MB);
    __bf16* ctx   = (__bf16*)(w + 48 * MB);
    __bf16* Kh    = (__bf16*)(w + 56 * MB);
    __bf16* W2T   = (__bf16*)(w + 56 * MB);
    __bf16* Vt    = (__bf16*)(w + 64 * MB);
    __bf16* W1T   = (__bf16*)(w + 64 * MB);
    __bf16* WqkvT = (__bf16*)(w + 72 * MB);
    __bf16* WoT   = (__bf16*)(w + 78 * MB);
    float*  bqkv  = (float*) (w + 80 * MB);

    convT_kernel<<<gConvD, blk, 0, stream>>>(Wq, WqkvT,               D_MODEL, D_MODEL);
    convT_kernel<<<gConvD, blk, 0, stream>>>(Wk, WqkvT + 1024 * 1024, D_MODEL, D_MODEL);
    convT_kernel<<<gConvD, blk, 0, stream>>>(Wv, WqkvT + 2048 * 1024, D_MODEL, D_MODEL);
    convT_kernel<<<gConvD, blk, 0, stream>>>(Wo, WoT, D_MODEL, D_MODEL);
    biascat_kernel<<<12, blk, 0, stream>>>(bq, bk, bv, bqkv);
    ln_kernel<<<ROWS, blk, 0, stream>>>(x, g1, b1, hln);
    gemm128<<<(ROWS / 128) * (3072 / 128), blk, 0, stream>>>(hln, WqkvT, bqkv, nullptr, qkv, ROWS, 3072, D_MODEL, 0, 0);
    rope_repack<<<ROWS, blk, 0, stream>>>(qkv, pos, Qh, Kh);
    vtrans_kernel<<<gVt, blk, 0, stream>>>(qkv + 2048, 3072, Vt, 1);
    attn_split<<<BATCH * NH * (SEQ / 64) * 2, blk, 0, stream>>>(Qh, Kh, Vt, pacc, pml);
    attn_combine<<<BATCH * NH * (SEQ / 64), blk, 0, stream>>>(pacc, pml, ctx);
    convT_kernel<<<gConv1, blk, 0, stream>>>(W1, W1T, D_MODEL, HID);
    convT_kernel<<<gConv2, blk, 0, stream>>>(W2, W2T, HID, D_MODEL);
    gemm64x128<<<(ROWS / 64) * (D_MODEL / 128), blk, 0, stream>>>(ctx, WoT, bo, x, x1, ROWS, D_MODEL, D_MODEL, 0, 1);
    ln_kernel<<<ROWS, blk, 0, stream>>>(x1, g2, b2, hln);
    gemm128<<<(ROWS / 128) * (HID / 128), blk, 0, stream>>>(hln, W1T, bm1, nullptr, hmlp, ROWS, HID, D_MODEL, 1, 0);
    gemm64x128<<<(ROWS / 64) * (D_MODEL / 128), blk, 0, stream>>>(hmlp, W2T, bm2, x1, out, ROWS, D_MODEL, HID, 0, 1);
  } else {
    // ---------------- 32 MB fallback ----------------
    __bf16* hln  = (__bf16*)(w + 0 * MB);
    __bf16* vlin = (__bf16*)(w + 8 * MB);
    __bf16* WqT  = (__bf16*)(w + 16 * MB);
    __bf16* WkT  = (__bf16*)(w + 18 * MB);
    __bf16* WvT  = (__bf16*)(w + 20 * MB);
    __bf16* ctx  = (__bf16*)(w + 16 * MB);
    __bf16* WoT  = (__bf16*)(w + 8 * MB);
    __bf16* W1T  = (__bf16*)(w + 8 * MB);
    __bf16* W2T  = (__bf16*)(w + 16 * MB);
    __bf16* Vt   = (__bf16*)(w + 24 * MB);
    __bf16* hmlp = (__bf16*)(w + 24 * MB);
    __bf16* qlin = (__bf16*)d_out;
    __bf16* klin = (__bf16*)d_out + (size_t)ROWS * D_MODEL;
    float*  x1   = (float*)d_out;

    convT_kernel<<<gConvD, blk, 0, stream>>>(Wq, WqT, D_MODEL, D_MODEL);
    convT_kernel<<<gConvD, blk, 0, stream>>>(Wk, WkT, D_MODEL, D_MODEL);
    convT_kernel<<<gConvD, blk, 0, stream>>>(Wv, WvT, D_MODEL, D_MODEL);
    ln_kernel<<<ROWS, blk, 0, stream>>>(x, g1, b1, hln);
    int nLin = (ROWS / 64) * (D_MODEL / 128);
    gemm64x128<<<nLin, blk, 0, stream>>>(hln, WqT, bq, nullptr, qlin, ROWS, D_MODEL, D_MODEL, 0, 0);
    gemm64x128<<<nLin, blk, 0, stream>>>(hln, WkT, bk, nullptr, klin, ROWS, D_MODEL, D_MODEL, 0, 0);
    gemm64x128<<<nLin, blk, 0, stream>>>(hln, WvT, bv, nullptr, vlin, ROWS, D_MODEL, D_MODEL, 0, 0);
    rope_inplace<<<ROWS, blk, 0, stream>>>(qlin, klin, pos, D_MODEL);
    vtrans_kernel<<<gVt, blk, 0, stream>>>(vlin, D_MODEL, Vt, 0);
    attn_kernel<<<BATCH * NH * (SEQ / 64), blk, 0, stream>>>(qlin, klin, Vt, ctx, D_MODEL);
    convT_kernel<<<gConvD, blk, 0, stream>>>(Wo, WoT, D_MODEL, D_MODEL);
    gemm64x128<<<nLin, blk, 0, stream>>>(ctx, WoT, bo, x, x1, ROWS, D_MODEL, D_MODEL, 0, 1);
    ln_kernel<<<ROWS, blk, 0, stream>>>(x1, g2, b2, hln);
    convT_kernel<<<gConv1, blk, 0, stream>>>(W1, W1T, D_MODEL, HID);
    convT_kernel<<<gConv2, blk, 0, stream>>>(W2, W2T, HID, D_MODEL);
    const int CH = 1024;
    for (int c = 0; c < ROWS / CH; ++c) {
      const __bf16* a1 = hln + (size_t)c * CH * D_MODEL;
      gemm128<<<(CH / 128) * (HID / 128), blk, 0, stream>>>(a1, W1T, bm1, nullptr, hmlp, CH, HID, D_MODEL, 1, 0);
      gemm64x128<<<(CH / 64) * (D_MODEL / 128), blk, 0, stream>>>(hmlp, W2T, bm2, x1 + (size_t)c * CH * D_MODEL,
                                          out + (size_t)c * CH * D_MODEL, CH, D_MODEL, HID, 0, 1);
    }
  }
}

// Round 9
// 464.850 us; speedup vs baseline: 2.4418x; 1.0505x over previous
//
#include <hip/hip_runtime.h>

typedef __bf16 bf16x8 __attribute__((ext_vector_type(8)));
typedef __bf16 bf16x4 __attribute__((ext_vector_type(4)));
typedef float  f32x4  __attribute__((ext_vector_type(4)));

#define D_MODEL 1024
#define SEQ     2048
#define BATCH   2
#define NH      16
#define DH      64
#define HID     4096
#define ROWS    (BATCH*SEQ)

static __device__ __forceinline__ void gl_lds16(const __bf16* g, __bf16* l) {
  __builtin_amdgcn_global_load_lds(
      (const __attribute__((address_space(1))) unsigned int*)g,
      (__attribute__((address_space(3))) unsigned int*)l, 16, 0, 0);
}

// ------------------------------------------- LayerNorm: fp32 in, bf16 out
__global__ __launch_bounds__(256) void ln_kernel(
    const float* __restrict__ x, const float* __restrict__ g,
    const float* __restrict__ b, __bf16* __restrict__ out)
{
  int row = blockIdx.x;
  const float* xr = x + (size_t)row * D_MODEL;
  int i0 = threadIdx.x * 4;
  f32x4 xv = *(const f32x4*)(xr + i0);
  float s  = xv[0] + xv[1] + xv[2] + xv[3];
  float ss = xv[0]*xv[0] + xv[1]*xv[1] + xv[2]*xv[2] + xv[3]*xv[3];
#pragma unroll
  for (int off = 1; off < 64; off <<= 1) {
    s  += __shfl_xor(s,  off, 64);
    ss += __shfl_xor(ss, off, 64);
  }
  __shared__ float red[8];
  int wave = threadIdx.x >> 6;
  if ((threadIdx.x & 63) == 0) { red[wave] = s; red[4 + wave] = ss; }
  __syncthreads();
  s  = red[0] + red[1] + red[2] + red[3];
  ss = red[4] + red[5] + red[6] + red[7];
  float mu  = s * (1.0f / D_MODEL);
  float var = ss * (1.0f / D_MODEL) - mu * mu;
  float inv = rsqrtf(var + 1e-5f);
  f32x4 gv = *(const f32x4*)(g + i0);
  f32x4 bv = *(const f32x4*)(b + i0);
  bf16x4 ov;
#pragma unroll
  for (int j = 0; j < 4; ++j)
    ov[j] = (__bf16)((xv[j] - mu) * inv * gv[j] + bv[j]);
  *(bf16x4*)(out + (size_t)row * D_MODEL + i0) = ov;
}

// ---------------------- Weight convert+transpose: fp32 [K][N] -> bf16 [N][K]
__global__ __launch_bounds__(256) void convT_kernel(
    const float* __restrict__ W, __bf16* __restrict__ Wt, int K, int N)
{
  __shared__ float T[32][33];
  int n0 = blockIdx.x * 32, k0 = blockIdx.y * 32;
  int r  = threadIdx.x >> 3;
  int c4 = (threadIdx.x & 7) * 4;
  f32x4 v = *(const f32x4*)(W + (size_t)(k0 + r) * N + n0 + c4);
#pragma unroll
  for (int i = 0; i < 4; ++i) T[r][c4 + i] = v[i];
  __syncthreads();
  bf16x4 o;
#pragma unroll
  for (int i = 0; i < 4; ++i) o[i] = (__bf16)T[c4 + i][r];
  *(bf16x4*)(Wt + (size_t)(n0 + r) * K + k0 + c4) = o;
}

// ------------------------------- Bias concat: [bq | bk | bv] -> bqkv (fp32)
__global__ void biascat_kernel(const float* __restrict__ a,
                               const float* __restrict__ b,
                               const float* __restrict__ c,
                               float* __restrict__ o)
{
  int i = blockIdx.x * 256 + threadIdx.x;
  o[i] = i < 1024 ? a[i] : (i < 2048 ? b[i - 1024] : c[i - 2048]);
}

// --------------- 128x128 GEMM, BK=64, XOR-swizzled LDS, XCD column panels.
// LDS layout: [row][slot], slot s holds K-chunk (s ^ (row&7)) of 8 elements.
__global__ __launch_bounds__(256) void gemm128(
    const __bf16* __restrict__ A, const __bf16* __restrict__ Bt,
    const float* __restrict__ bias, const float* __restrict__ resid,
    void* __restrict__ Cv, int M, int N, int K, int act, int c_fp32)
{
  __shared__ __bf16 As[128 * 64];   // 16 KB
  __shared__ __bf16 Bs[128 * 64];   // 16 KB
  int tid = threadIdx.x, lane = tid & 63, wv = tid >> 6;
  int quad = lane >> 4, l16 = lane & 15;
  int wr = wv >> 1, wc = wv & 1;
  int gx = M >> 7, gy = N >> 7;
  int blk = blockIdx.x;
  int xcd = blk & 7, t = blk >> 3;
  int row0 = (t % gx) * 128;
  int col0 = (xcd * (gy >> 3) + t / gx) * 128;
  int s_r8 = lane >> 3;             // row-within-8
  int s_c8 = lane & 7;              // dest slot
  int s_src = (s_c8 ^ s_r8) * 8;    // source K-chunk offset (swizzle)
  int sw = l16 & 7;                 // fragment de-swizzle
  f32x4 acc[4][4] = {};

  for (int k0 = 0; k0 < K; k0 += 64) {
#pragma unroll
    for (int p = 0; p < 4; ++p) {
      int r = p * 32 + wv * 8 + s_r8;
      gl_lds16(A  + (size_t)(row0 + r) * K + k0 + s_src, As + p * 2048 + wv * 512);
      gl_lds16(Bt + (size_t)(col0 + r) * K + k0 + s_src, Bs + p * 2048 + wv * 512);
    }
    __syncthreads();
#pragma unroll
    for (int kk = 0; kk < 2; ++kk) {
      int slot = ((kk * 4 + quad) ^ sw) * 8;
      bf16x8 af[4], bf[4];
#pragma unroll
      for (int i = 0; i < 4; ++i) {
        af[i] = *(const bf16x8*)(As + (wr * 64 + i * 16 + l16) * 64 + slot);
        bf[i] = *(const bf16x8*)(Bs + (wc * 64 + i * 16 + l16) * 64 + slot);
      }
#pragma unroll
      for (int i = 0; i < 4; ++i)
#pragma unroll
        for (int j = 0; j < 4; ++j)
          acc[i][j] = __builtin_amdgcn_mfma_f32_16x16x32_bf16(af[i], bf[j], acc[i][j], 0, 0, 0);
    }
    __syncthreads();
  }
#pragma unroll
  for (int i = 0; i < 4; ++i) {
    int grow = row0 + wr * 64 + i * 16 + quad * 4;
#pragma unroll
    for (int j = 0; j < 4; ++j) {
      int gcol = col0 + wc * 64 + j * 16 + l16;
      float bsv = bias[gcol];
#pragma unroll
      for (int r = 0; r < 4; ++r) {
        size_t off = (size_t)(grow + r) * N + gcol;
        float v = acc[i][j][r] + bsv;
        if (act) v = 0.5f * v * (1.0f + erff(v * 0.70710678118654752f));
        if (resid) v += resid[off];
        if (c_fp32) ((float*)Cv)[off] = v;
        else        ((__bf16*)Cv)[off] = (__bf16)v;
      }
    }
  }
}

// ---------- 64x128-tile GEMM (N=1024 outputs), BK=64, swizzled, XCD panels
__global__ __launch_bounds__(256) void gemm64x128(
    const __bf16* __restrict__ A, const __bf16* __restrict__ Bt,
    const float* __restrict__ bias, const float* __restrict__ resid,
    void* __restrict__ Cv, int M, int N, int K, int act, int c_fp32)
{
  __shared__ __bf16 As[64 * 64];    // 8 KB
  __shared__ __bf16 Bs[128 * 64];   // 16 KB
  int tid = threadIdx.x, lane = tid & 63, wv = tid >> 6;
  int quad = lane >> 4, l16 = lane & 15;
  int wr = wv >> 1, wc = wv & 1;
  int gx = M >> 6, gy = N >> 7;
  int blk = blockIdx.x;
  int xcd = blk & 7, t = blk >> 3;
  int row0 = (t % gx) * 64;
  int col0 = (xcd * (gy >> 3) + t / gx) * 128;
  int s_r8 = lane >> 3;
  int s_c8 = lane & 7;
  int s_src = (s_c8 ^ s_r8) * 8;
  int sw = l16 & 7;
  f32x4 acc[2][4] = {};

  for (int k0 = 0; k0 < K; k0 += 64) {
#pragma unroll
    for (int p = 0; p < 4; ++p) {
      int r = p * 32 + wv * 8 + s_r8;
      if (p < 2)
        gl_lds16(A + (size_t)(row0 + r) * K + k0 + s_src, As + p * 2048 + wv * 512);
      gl_lds16(Bt + (size_t)(col0 + r) * K + k0 + s_src, Bs + p * 2048 + wv * 512);
    }
    __syncthreads();
#pragma unroll
    for (int kk = 0; kk < 2; ++kk) {
      int slot = ((kk * 4 + quad) ^ sw) * 8;
      bf16x8 af[2], bf[4];
#pragma unroll
      for (int i = 0; i < 2; ++i)
        af[i] = *(const bf16x8*)(As + (wr * 32 + i * 16 + l16) * 64 + slot);
#pragma unroll
      for (int j = 0; j < 4; ++j)
        bf[j] = *(const bf16x8*)(Bs + (wc * 64 + j * 16 + l16) * 64 + slot);
#pragma unroll
      for (int i = 0; i < 2; ++i)
#pragma unroll
        for (int j = 0; j < 4; ++j)
          acc[i][j] = __builtin_amdgcn_mfma_f32_16x16x32_bf16(af[i], bf[j], acc[i][j], 0, 0, 0);
    }
    __syncthreads();
  }
#pragma unroll
  for (int i = 0; i < 2; ++i) {
    int grow = row0 + wr * 32 + i * 16 + quad * 4;
#pragma unroll
    for (int j = 0; j < 4; ++j) {
      int gcol = col0 + wc * 64 + j * 16 + l16;
      float bsv = bias[gcol];
#pragma unroll
      for (int r = 0; r < 4; ++r) {
        size_t off = (size_t)(grow + r) * N + gcol;
        float v = acc[i][j][r] + bsv;
        if (act) v = 0.5f * v * (1.0f + erff(v * 0.70710678118654752f));
        if (resid) v += resid[off];
        if (c_fp32) ((float*)Cv)[off] = v;
        else        ((__bf16*)Cv)[off] = (__bf16)v;
      }
    }
  }
}

// ------------------------- RoPE + repack qkv -> per-head Qh/Kh [bh][SEQ][64]
__global__ __launch_bounds__(256) void rope_repack(
    const __bf16* __restrict__ qkv, const int* __restrict__ pos,
    __bf16* __restrict__ Qh, __bf16* __restrict__ Kh)
{
  int row = blockIdx.x;
  int b = row >> 11, n = row & (SEQ - 1);
  float p = (float)pos[n];
  const __bf16* qr = qkv + (size_t)row * 3072;
#pragma unroll
  for (int t = 0; t < 2; ++t) {
    int i = threadIdx.x + t * 256;      // 0..511
    float fr  = expf(-9.210340371976184f * ((float)i * (1.0f / 512.0f)));
    float ang = p * fr;
    float sn, c;
    sincosf(ang, &sn, &c);
    float q1 = (float)qr[i],        q2 = (float)qr[512 + i];
    float k1 = (float)qr[1024 + i], k2 = (float)qr[1536 + i];
    int h1 = i >> 6, d1 = i & 63;
    int h2 = (i + 512) >> 6;
    size_t o1 = ((size_t)(b * NH + h1) * SEQ + n) * DH + d1;
    size_t o2 = ((size_t)(b * NH + h2) * SEQ + n) * DH + d1;
    Qh[o1] = (__bf16)(q1 * c - q2 * sn);
    Qh[o2] = (__bf16)(q1 * sn + q2 * c);
    Kh[o1] = (__bf16)(k1 * c - k2 * sn);
    Kh[o2] = (__bf16)(k1 * sn + k2 * c);
  }
}

// ----- V transpose. blocked=0: Vt[bh][64][SEQ]; blocked=1: Vt[bh][seg][64][128]
__global__ __launch_bounds__(256) void vtrans_kernel(
    const __bf16* __restrict__ Vsrc, int vstride, __bf16* __restrict__ Vt,
    int blocked)
{
  __shared__ __bf16 T[64][72];
  int bh = blockIdx.x;
  int kb = blockIdx.y * 64;
  int b = bh >> 4, h = bh & 15;
  int tid = threadIdx.x;
#pragma unroll
  for (int t = 0; t < 2; ++t) {
    int u = tid + t * 256;
    int r = u >> 3, seg = (u & 7) * 8;
    bf16x8 v = *(const bf16x8*)(Vsrc + (size_t)(b * SEQ + kb + r) * vstride + h * DH + seg);
    *(bf16x8*)(&T[r][seg]) = v;
  }
  __syncthreads();
#pragma unroll
  for (int t = 0; t < 2; ++t) {
    int u = tid + t * 256;
    int d = u >> 3, ks = (u & 7) * 8;
    bf16x8 o;
#pragma unroll
    for (int i = 0; i < 8; ++i) o[i] = T[ks + i][d];
    if (blocked) {
      int key = kb + ks;
      *(bf16x8*)(Vt + (((size_t)bh * (SEQ / 128) + (key >> 7)) * DH + d) * 128 + (key & 127)) = o;
    } else {
      *(bf16x8*)(Vt + ((size_t)bh * DH + d) * SEQ + kb + ks) = o;
    }
  }
}

// --- Flash attention, split-K=2, LDS K/V tiles (XOR-swizzled), XCD swizzle.
#define KS 136
__global__ __launch_bounds__(256) void attn_split(
    const __bf16* __restrict__ Qh, const __bf16* __restrict__ Kh,
    const __bf16* __restrict__ Vt, __bf16* __restrict__ pacc,
    float* __restrict__ pml)
{
  __shared__ __bf16 Ks[128 * 64];      // [key][slot], slot = seg ^ ((key>>3)&7)
  __shared__ __bf16 Vs[64 * 128];      // [d][slot], slot = seg ^ (d&15)
  __shared__ __bf16 Pl[4][16 * KS];    // per-wave P [qrow][key]
  int tid = threadIdx.x, lane = tid & 63, wave = tid >> 6;
  int quad = lane >> 4, l16 = lane & 15;
  int blk = blockIdx.x;
  int split = blk >> 10;
  int rr = blk & 1023;
  int bh  = ((rr & 7) << 2) | ((rr >> 3) & 3);
  int q64 = rr >> 5;
  int q0 = q64 * 64 + wave * 16;
  const __bf16* qbase = Qh + (size_t)bh * SEQ * DH;
  const __bf16* kbase = Kh + (size_t)bh * SEQ * DH;
  const __bf16* vbase = Vt + (size_t)bh * SEQ * DH;   // blocked layout
  const __bf16* qp = qbase + (size_t)(q0 + l16) * DH + quad * 8;
  bf16x8 qf0 = *(const bf16x8*)(qp);
  bf16x8 qf1 = *(const bf16x8*)(qp + 32);
  float mrow[4] = {-1e30f, -1e30f, -1e30f, -1e30f};
  float lrow[4] = {0.f, 0.f, 0.f, 0.f};
  f32x4 acc[4] = {};
  __bf16* pw = &Pl[wave][0];
  int s_kr = lane >> 3;                // K row within issue: 0..7
  int s_k8 = lane & 7;                 // K slot: 0..7
  int s_vd = lane >> 4;                // V d within issue: 0..3
  int s_vs = lane & 15;                // V slot: 0..15
  int sw8  = l16 & 7;                  // K read swizzle

  int kb0 = split * (SEQ / 2);
  for (int it = 0; it < (SEQ / 2) / 128; ++it) {
    int kb = kb0 + it * 128;
    const __bf16* kt = kbase + (size_t)kb * DH;
    const __bf16* vt = vbase + (size_t)(kb >> 7) * (DH * 128);
    __syncthreads();                   // prev tile fully consumed
#pragma unroll
    for (int p = 0; p < 4; ++p) {
      int key0 = p * 32 + wave * 8;
      int swz  = (key0 >> 3) & 7;
      gl_lds16(kt + (key0 + s_kr) * DH + ((s_k8 ^ swz) * 8), Ks + p * 2048 + wave * 512);
      int d = p * 16 + wave * 4 + s_vd;
      gl_lds16(vt + d * 128 + ((s_vs ^ (d & 15)) * 8), Vs + p * 2048 + wave * 512);
    }
    __syncthreads();                   // staging complete
    // scores: key = l16*8 + j; K slots de-swizzled by quad^sw8
    f32x4 s[8];
#pragma unroll
    for (int j = 0; j < 8; ++j) {
      const __bf16* kr = Ks + (l16 * 8 + j) * 64;
      bf16x8 kf0 = *(const bf16x8*)(kr + (quad ^ sw8) * 8);
      bf16x8 kf1 = *(const bf16x8*)(kr + ((quad ^ sw8) ^ 4) * 8);
      f32x4 z = {};
      z = __builtin_amdgcn_mfma_f32_16x16x32_bf16(qf0, kf0, z, 0, 0, 0);
      z = __builtin_amdgcn_mfma_f32_16x16x32_bf16(qf1, kf1, z, 0, 0, 0);
#pragma unroll
      for (int r = 0; r < 4; ++r) s[j][r] = z[r] * 0.125f;   // 1/sqrt(64)
    }
#pragma unroll
    for (int r = 0; r < 4; ++r) {
      float mx = s[0][r];
#pragma unroll
      for (int j = 1; j < 8; ++j) mx = fmaxf(mx, s[j][r]);
#pragma unroll
      for (int off = 1; off < 16; off <<= 1) mx = fmaxf(mx, __shfl_xor(mx, off, 64));
      float mn = fmaxf(mrow[r], mx);
      float al = __expf(mrow[r] - mn);
      float p[8], rs = 0.f;
#pragma unroll
      for (int j = 0; j < 8; ++j) { p[j] = __expf(s[j][r] - mn); rs += p[j]; }
#pragma unroll
      for (int off = 1; off < 16; off <<= 1) rs += __shfl_xor(rs, off, 64);
      lrow[r] = lrow[r] * al + rs;
      mrow[r] = mn;
#pragma unroll
      for (int j = 0; j < 4; ++j) acc[j][r] *= al;
      bf16x8 pv;
#pragma unroll
      for (int j = 0; j < 8; ++j) pv[j] = (__bf16)p[j];
      *(bf16x8*)(pw + (quad * 4 + r) * KS + l16 * 8) = pv;
    }
    // PV: P per-wave (lgkmcnt-ordered), V fragments from swizzled LDS
#pragma unroll
    for (int kk = 0; kk < 4; ++kk) {
      bf16x8 pf = *(const bf16x8*)(pw + l16 * KS + kk * 32 + quad * 8);
#pragma unroll
      for (int j = 0; j < 4; ++j) {
        int d = j * 16 + l16;
        bf16x8 vf = *(const bf16x8*)(Vs + d * 128 + (((kk * 4 + quad) ^ (d & 15)) * 8));
        acc[j] = __builtin_amdgcn_mfma_f32_16x16x32_bf16(pf, vf, acc[j], 0, 0, 0);
      }
    }
  }
  // partial outputs: unnormalized acc (bf16) + m,l (fp32)
#pragma unroll
  for (int r = 0; r < 4; ++r) {
    int brow = wave * 16 + quad * 4 + r;
#pragma unroll
    for (int j = 0; j < 4; ++j)
      pacc[((size_t)blk * 64 + brow) * 64 + j * 16 + l16] = (__bf16)acc[j][r];
    if (l16 == 0) {
      pml[(size_t)blk * 128 + brow]      = mrow[r];
      pml[(size_t)blk * 128 + 64 + brow] = lrow[r];
    }
  }
}

// ------------------------------------------- combine 2 splits -> ctx (bf16)
__global__ __launch_bounds__(256) void attn_combine(
    const __bf16* __restrict__ pacc, const float* __restrict__ pml,
    __bf16* __restrict__ ctx)
{
  int bq = blockIdx.x;                // bh*32 + q64
  int q64 = bq & 31, bh = bq >> 5;
  int b = bh >> 4, h = bh & 15;
  int tid = threadIdx.x;
  int r = tid >> 2;                   // 0..63
  int c = (tid & 3) * 16;
  int blk0 = ((q64 * 4 + (bh & 3)) << 3) | (bh >> 2);   // split 0 (XCD swizzle)
  int blk1 = blk0 + 1024;                               // split 1
  float m0 = pml[(size_t)blk0 * 128 + r], l0 = pml[(size_t)blk0 * 128 + 64 + r];
  float m1 = pml[(size_t)blk1 * 128 + r], l1 = pml[(size_t)blk1 * 128 + 64 + r];
  float m = fmaxf(m0, m1);
  float w0 = __expf(m0 - m), w1 = __expf(m1 - m);
  float inv = 1.0f / (w0 * l0 + w1 * l1);
  size_t r0 = ((size_t)blk0 * 64 + r) * 64 + c;
  size_t r1 = ((size_t)blk1 * 64 + r) * 64 + c;
  size_t ob = ((size_t)(b * SEQ) + q64 * 64 + r) * D_MODEL + h * DH + c;
#pragma unroll
  for (int g = 0; g < 2; ++g) {
    bf16x8 a0 = *(const bf16x8*)(pacc + r0 + g * 8);
    bf16x8 a1 = *(const bf16x8*)(pacc + r1 + g * 8);
    bf16x8 o;
#pragma unroll
    for (int i = 0; i < 8; ++i)
      o[i] = (__bf16)((w0 * (float)a0[i] + w1 * (float)a1[i]) * inv);
    *(bf16x8*)(ctx + ob + g * 8) = o;
  }
}

// ------------ legacy kernels for the small-workspace fallback path ------------
__global__ __launch_bounds__(256) void rope_inplace(
    __bf16* __restrict__ ql, __bf16* __restrict__ kl,
    const int* __restrict__ pos, int stride)
{
  int row = blockIdx.x;
  int n = row & (SEQ - 1);
  float p = (float)pos[n];
  const size_t rbase = (size_t)row * stride;
#pragma unroll
  for (int t = 0; t < 2; ++t) {
    int i = threadIdx.x + t * 256;
    float fr  = expf(-9.210340371976184f * ((float)i * (1.0f / 512.0f)));
    float ang = p * fr;
    float sn, c;
    sincosf(ang, &sn, &c);
    float q1 = (float)ql[rbase + i], q2 = (float)ql[rbase + 512 + i];
    float k1 = (float)kl[rbase + i], k2 = (float)kl[rbase + 512 + i];
    ql[rbase + i]       = (__bf16)(q1 * c - q2 * sn);
    ql[rbase + 512 + i] = (__bf16)(q1 * sn + q2 * c);
    kl[rbase + i]       = (__bf16)(k1 * c - k2 * sn);
    kl[rbase + 512 + i] = (__bf16)(k1 * sn + k2 * c);
  }
}

__global__ __launch_bounds__(256) void attn_kernel(
    const __bf16* __restrict__ Q, const __bf16* __restrict__ K,
    const __bf16* __restrict__ Vt, __bf16* __restrict__ ctx, int qkstride)
{
  __shared__ __bf16 Pl[4][16 * KS];
  int tid = threadIdx.x, lane = tid & 63, wave = tid >> 6;
  int quad = lane >> 4, l16 = lane & 15;
  int blk = blockIdx.x;
  int q64 = blk & 31;
  int bh  = blk >> 5;
  int b = bh >> 4, h = bh & 15;
  int q0 = q64 * 64 + wave * 16;
  const __bf16* qbase = Q + (size_t)b * SEQ * qkstride + h * DH;
  const __bf16* kbase = K + (size_t)b * SEQ * qkstride + h * DH;
  const __bf16* vbase = Vt + (size_t)bh * DH * SEQ;
  const __bf16* qp = qbase + (size_t)(q0 + l16) * qkstride + quad * 8;
  bf16x8 qf0 = *(const bf16x8*)(qp);
  bf16x8 qf1 = *(const bf16x8*)(qp + 32);
  float mrow[4] = {-1e30f, -1e30f, -1e30f, -1e30f};
  float lrow[4] = {0.f, 0.f, 0.f, 0.f};
  f32x4 acc[4] = {};
  __bf16* pw = &Pl[wave][0];

  for (int kb = 0; kb < SEQ; kb += 128) {
    f32x4 s[8];
#pragma unroll
    for (int j = 0; j < 8; ++j) {
      const __bf16* kp = kbase + (size_t)(kb + l16 * 8 + j) * qkstride + quad * 8;
      bf16x8 kf0 = *(const bf16x8*)(kp);
      bf16x8 kf1 = *(const bf16x8*)(kp + 32);
      f32x4 z = {};
      z = __builtin_amdgcn_mfma_f32_16x16x32_bf16(qf0, kf0, z, 0, 0, 0);
      z = __builtin_amdgcn_mfma_f32_16x16x32_bf16(qf1, kf1, z, 0, 0, 0);
#pragma unroll
      for (int r = 0; r < 4; ++r) s[j][r] = z[r] * 0.125f;
    }
#pragma unroll
    for (int r = 0; r < 4; ++r) {
      float mx = s[0][r];
#pragma unroll
      for (int j = 1; j < 8; ++j) mx = fmaxf(mx, s[j][r]);
#pragma unroll
      for (int off = 1; off < 16; off <<= 1) mx = fmaxf(mx, __shfl_xor(mx, off, 64));
      float mn = fmaxf(mrow[r], mx);
      float al = __expf(mrow[r] - mn);
      float p[8], rs = 0.f;
#pragma unroll
      for (int j = 0; j < 8; ++j) { p[j] = __expf(s[j][r] - mn); rs += p[j]; }
#pragma unroll
      for (int off = 1; off < 16; off <<= 1) rs += __shfl_xor(rs, off, 64);
      lrow[r] = lrow[r] * al + rs;
      mrow[r] = mn;
#pragma unroll
      for (int j = 0; j < 4; ++j) acc[j][r] *= al;
      bf16x8 pv;
#pragma unroll
      for (int j = 0; j < 8; ++j) pv[j] = (__bf16)p[j];
      *(bf16x8*)(pw + (quad * 4 + r) * KS + l16 * 8) = pv;
    }
#pragma unroll
    for (int kk = 0; kk < 4; ++kk) {
      bf16x8 pf = *(const bf16x8*)(pw + l16 * KS + kk * 32 + quad * 8);
#pragma unroll
      for (int j = 0; j < 4; ++j) {
        bf16x8 vf = *(const bf16x8*)(vbase + (size_t)(j * 16 + l16) * SEQ + kb + kk * 32 + quad * 8);
        acc[j] = __builtin_amdgcn_mfma_f32_16x16x32_bf16(pf, vf, acc[j], 0, 0, 0);
      }
    }
  }
#pragma unroll
  for (int r = 0; r < 4; ++r) {
    int row = q0 + quad * 4 + r;
    float inv = 1.0f / lrow[r];
    size_t obase = ((size_t)(b * SEQ) + row) * D_MODEL + h * DH;
#pragma unroll
    for (int j = 0; j < 4; ++j)
      ctx[obase + j * 16 + l16] = (__bf16)(acc[j][r] * inv);
  }
}

// ------------------------------------------------------------------ launcher
extern "C" void kernel_launch(void* const* d_in, const int* in_sizes, int n_in,
                              void* d_out, int out_size, void* d_ws, size_t ws_size,
                              hipStream_t stream)
{
  const float* x   = (const float*)d_in[0];
  const int*   pos = (const int*)  d_in[1];
  const float* Wq  = (const float*)d_in[2];
  const float* bq  = (const float*)d_in[3];
  const float* Wk  = (const float*)d_in[4];
  const float* bk  = (const float*)d_in[5];
  const float* Wv  = (const float*)d_in[6];
  const float* bv  = (const float*)d_in[7];
  const float* Wo  = (const float*)d_in[8];
  const float* bo  = (const float*)d_in[9];
  const float* g1  = (const float*)d_in[10];
  const float* b1  = (const float*)d_in[11];
  const float* g2  = (const float*)d_in[12];
  const float* b2  = (const float*)d_in[13];
  const float* W1  = (const float*)d_in[14];
  const float* bm1 = (const float*)d_in[15];
  const float* W2  = (const float*)d_in[16];
  const float* bm2 = (const float*)d_in[17];
  float* out = (float*)d_out;

  const size_t MB = 1024 * 1024;
  char* w = (char*)d_ws;
  dim3 blk(256);
  dim3 gConvD(D_MODEL / 32, D_MODEL / 32);
  dim3 gConv1(HID / 32, D_MODEL / 32);
  dim3 gConv2(D_MODEL / 32, HID / 32);
  dim3 gVt(BATCH * NH, SEQ / 64);

  if (ws_size >= (size_t)96 * MB) {
    // ---------------- large path ----------------
    __bf16* hln   = (__bf16*)(w + 0 * MB);
    float*  x1    = (float*) (w + 8 * MB);
    __bf16* qkv   = (__bf16*)(w + 24 * MB);
    __bf16* pacc  = (__bf16*)(w + 24 * MB);
    float*  pml   = (float*) (w + 41 * MB);
    __bf16* hmlp  = (__bf16*)(w + 24 * MB);
    __bf16* Qh    = (__bf16*)(w + 48 * MB);
    __bf16* ctx   = (__bf16*)(w + 48 * MB);
    __bf16* Kh    = (__bf16*)(w + 56 * MB);
    __bf16* W2T   = (__bf16*)(w + 56 * MB);
    __bf16* Vt    = (__bf16*)(w + 64 * MB);
    __bf16* W1T   = (__bf16*)(w + 64 * MB);
    __bf16* WqkvT = (__bf16*)(w + 72 * MB);
    __bf16* WoT   = (__bf16*)(w + 78 * MB);
    float*  bqkv  = (float*) (w + 80 * MB);

    convT_kernel<<<gConvD, blk, 0, stream>>>(Wq, WqkvT,               D_MODEL, D_MODEL);
    convT_kernel<<<gConvD, blk, 0, stream>>>(Wk, WqkvT + 1024 * 1024, D_MODEL, D_MODEL);
    convT_kernel<<<gConvD, blk, 0, stream>>>(Wv, WqkvT + 2048 * 1024, D_MODEL, D_MODEL);
    convT_kernel<<<gConvD, blk, 0, stream>>>(Wo, WoT, D_MODEL, D_MODEL);
    biascat_kernel<<<12, blk, 0, stream>>>(bq, bk, bv, bqkv);
    ln_kernel<<<ROWS, blk, 0, stream>>>(x, g1, b1, hln);
    gemm128<<<(ROWS / 128) * (3072 / 128), blk, 0, stream>>>(hln, WqkvT, bqkv, nullptr, qkv, ROWS, 3072, D_MODEL, 0, 0);
    rope_repack<<<ROWS, blk, 0, stream>>>(qkv, pos, Qh, Kh);
    vtrans_kernel<<<gVt, blk, 0, stream>>>(qkv + 2048, 3072, Vt, 1);
    attn_split<<<BATCH * NH * (SEQ / 64) * 2, blk, 0, stream>>>(Qh, Kh, Vt, pacc, pml);
    attn_combine<<<BATCH * NH * (SEQ / 64), blk, 0, stream>>>(pacc, pml, ctx);
    convT_kernel<<<gConv1, blk, 0, stream>>>(W1, W1T, D_MODEL, HID);
    convT_kernel<<<gConv2, blk, 0, stream>>>(W2, W2T, HID, D_MODEL);
    gemm64x128<<<(ROWS / 64) * (D_MODEL / 128), blk, 0, stream>>>(ctx, WoT, bo, x, x1, ROWS, D_MODEL, D_MODEL, 0, 1);
    ln_kernel<<<ROWS, blk, 0, stream>>>(x1, g2, b2, hln);
    gemm128<<<(ROWS / 128) * (HID / 128), blk, 0, stream>>>(hln, W1T, bm1, nullptr, hmlp, ROWS, HID, D_MODEL, 1, 0);
    gemm64x128<<<(ROWS / 64) * (D_MODEL / 128), blk, 0, stream>>>(hmlp, W2T, bm2, x1, out, ROWS, D_MODEL, HID, 0, 1);
  } else {
    // ---------------- 32 MB fallback ----------------
    __bf16* hln  = (__bf16*)(w + 0 * MB);
    __bf16* vlin = (__bf16*)(w + 8 * MB);
    __bf16* WqT  = (__bf16*)(w + 16 * MB);
    __bf16* WkT  = (__bf16*)(w + 18 * MB);
    __bf16* WvT  = (__bf16*)(w + 20 * MB);
    __bf16* ctx  = (__bf16*)(w + 16 * MB);
    __bf16* WoT  = (__bf16*)(w + 8 * MB);
    __bf16* W1T  = (__bf16*)(w + 8 * MB);
    __bf16* W2T  = (__bf16*)(w + 16 * MB);
    __bf16* Vt   = (__bf16*)(w + 24 * MB);
    __bf16* hmlp = (__bf16*)(w + 24 * MB);
    __bf16* qlin = (__bf16*)d_out;
    __bf16* klin = (__bf16*)d_out + (size_t)ROWS * D_MODEL;
    float*  x1   = (float*)d_out;

    convT_kernel<<<gConvD, blk, 0, stream>>>(Wq, WqT, D_MODEL, D_MODEL);
    convT_kernel<<<gConvD, blk, 0, stream>>>(Wk, WkT, D_MODEL, D_MODEL);
    convT_kernel<<<gConvD, blk, 0, stream>>>(Wv, WvT, D_MODEL, D_MODEL);
    ln_kernel<<<ROWS, blk, 0, stream>>>(x, g1, b1, hln);
    int nLin = (ROWS / 64) * (D_MODEL / 128);
    gemm64x128<<<nLin, blk, 0, stream>>>(hln, WqT, bq, nullptr, qlin, ROWS, D_MODEL, D_MODEL, 0, 0);
    gemm64x128<<<nLin, blk, 0, stream>>>(hln, WkT, bk, nullptr, klin, ROWS, D_MODEL, D_MODEL, 0, 0);
    gemm64x128<<<nLin, blk, 0, stream>>>(hln, WvT, bv, nullptr, vlin, ROWS, D_MODEL, D_MODEL, 0, 0);
    rope_inplace<<<ROWS, blk, 0, stream>>>(qlin, klin, pos, D_MODEL);
    vtrans_kernel<<<gVt, blk, 0, stream>>>(vlin, D_MODEL, Vt, 0);
    attn_kernel<<<BATCH * NH * (SEQ / 64), blk, 0, stream>>>(qlin, klin, Vt, ctx, D_MODEL);
    convT_kernel<<<gConvD, blk, 0, stream>>>(Wo, WoT, D_MODEL, D_MODEL);
    gemm64x128<<<nLin, blk, 0, stream>>>(ctx, WoT, bo, x, x1, ROWS, D_MODEL, D_MODEL, 0, 1);
    ln_kernel<<<ROWS, blk, 0, stream>>>(x1, g2, b2, hln);
    convT_kernel<<<gConv1, blk, 0, stream>>>(W1, W1T, D_MODEL, HID);
    convT_kernel<<<gConv2, blk, 0, stream>>>(W2, W2T, HID, D_MODEL);
    const int CH = 1024;
    for (int c = 0; c < ROWS / CH; ++c) {
      const __bf16* a1 = hln + (size_t)c * CH * D_MODEL;
      gemm128<<<(CH / 128) * (HID / 128), blk, 0, stream>>>(a1, W1T, bm1, nullptr, hmlp, CH, HID, D_MODEL, 1, 0);
      gemm64x128<<<(CH / 64) * (D_MODEL / 128), blk, 0, stream>>>(hmlp, W2T, bm2, x1 + (size_t)c * CH * D_MODEL,
                                          out + (size_t)c * CH * D_MODEL, CH, D_MODEL, HID, 0, 1);
    }
  }
}